// Round 9
// baseline (420.504 us; speedup 1.0000x reference)
//
#include <hip/hip_runtime.h>
#include <math.h>

typedef unsigned short ushort_t;
typedef short bf16x8 __attribute__((ext_vector_type(8)));
typedef unsigned short u16x8 __attribute__((ext_vector_type(8)));
typedef float f32x4 __attribute__((ext_vector_type(4)));

__device__ __forceinline__ float wsum64(float v) {
#pragma unroll
  for (int off = 32; off > 0; off >>= 1) v += __shfl_xor(v, off, 64);
  return v;
}

__device__ __forceinline__ ushort_t f2bf(float x) {   // RNE f32->bf16
  unsigned u = __float_as_uint(x);
  return (ushort_t)((u + 0x7fffu + ((u >> 16) & 1u)) >> 16);
}
__device__ __forceinline__ float bf2f(ushort_t h) {
  return __uint_as_float(((unsigned)h) << 16);
}

__device__ __forceinline__ void split8(const float4 a, const float4 b,
                                       u16x8& h, u16x8& l) {
  h[0]=f2bf(a.x); l[0]=f2bf(a.x-bf2f(h[0]));
  h[1]=f2bf(a.y); l[1]=f2bf(a.y-bf2f(h[1]));
  h[2]=f2bf(a.z); l[2]=f2bf(a.z-bf2f(h[2]));
  h[3]=f2bf(a.w); l[3]=f2bf(a.w-bf2f(h[3]));
  h[4]=f2bf(b.x); l[4]=f2bf(b.x-bf2f(h[4]));
  h[5]=f2bf(b.y); l[5]=f2bf(b.y-bf2f(h[5]));
  h[6]=f2bf(b.z); l[6]=f2bf(b.z-bf2f(h[6]));
  h[7]=f2bf(b.w); l[7]=f2bf(b.w-bf2f(h[7]));
}

// async global(per-lane) -> LDS(wave-uniform base + lane*16B), 16B per lane
__device__ __forceinline__ void gl16(const void* g, const void* l) {
  __builtin_amdgcn_global_load_lds(
      (const __attribute__((address_space(1))) unsigned int*)g,
      (__attribute__((address_space(3))) unsigned int*)l, 16, 0, 0);
}

#define SBAR __builtin_amdgcn_sched_barrier(0)
#define BARRIER __builtin_amdgcn_s_barrier()
#define LGKM0 asm volatile("s_waitcnt lgkmcnt(0)" ::: "memory")
#define VMC0 asm volatile("s_waitcnt vmcnt(0)" ::: "memory")

// ---------------------------------------------------------------------------
// gather-split: Ah/Al[row][512] bf16 hi/lo of embed[seq[row]]
// ---------------------------------------------------------------------------
__global__ __launch_bounds__(256)
void gather_split(const int* __restrict__ seq, const float* __restrict__ embed,
                  ushort_t* __restrict__ Ah, ushort_t* __restrict__ Al)
{
  const int wid = threadIdx.x >> 6, lane = threadIdx.x & 63;
  const int row = blockIdx.x * 4 + wid;
  const float* src = embed + (size_t)seq[row] * 512 + lane * 8;
  const float4 a = *(const float4*)src;
  const float4 b = *(const float4*)(src + 4);
  u16x8 h, l;
  split8(a, b, h, l);
  *(u16x8*)(Ah + (size_t)row * 512 + lane * 8) = h;
  *(u16x8*)(Al + (size_t)row * 512 + lane * 8) = l;
}

// elementwise weight split (n8 = total_elems/8)
__global__ __launch_bounds__(256)
void split_w(const float* __restrict__ W, ushort_t* __restrict__ Wh,
             ushort_t* __restrict__ Wl, int n8)
{
  const int i = blockIdx.x * 256 + threadIdx.x;
  if (i >= n8) return;
  const float4 a = *(const float4*)(W + (size_t)i * 8);
  const float4 b = *(const float4*)(W + (size_t)i * 8 + 4);
  u16x8 h, l;
  split8(a, b, h, l);
  *(u16x8*)(Wh + (size_t)i * 8) = h;
  *(u16x8*)(Wl + (size_t)i * 8) = l;
}

// ---------------------------------------------------------------------------
// Split-bf16 MFMA GEMM as virtual K'=3K bf16 GEMM (A'=[Ah|Al|Ah], B'=[Bh|Bh|Bl]).
// 128x128 tile, 4 waves (2Mx2N), per-wave 64x64 = acc[4][4]. BK=32 virtual.
// LDS 32 KB = 2 dbuf x (A 8KB + B 8KB) -> 3 blocks/CU (12 waves: m114 overlap
// is the fix for the 36%-MfmaUtil latency wall seen at 2 blocks/CU).
// LDS layout per matrix tile (128 rows x 32 cols bf16): row-PAIRS of 128 B
// (8 chunks x 16 B); LDS chunk c of pair p holds global chunk g = c ^ (p&7),
// where g -> row 2p+(g>>2), col (g&3)*8. Fragment ds_read_b128 pattern is
// uniform 2-way banked (free, m136); gl16 dests stay linear, sources
// pre-swizzled (m173). Per tile: {8 ds_read + 4 gl16 stage + 16 MFMA},
// one vmcnt(0)+barrier per tile.
// EPI 0: +bias, relu -> Oh/Ol bf16 hi/lo (8KB-per-wave LDS bounce, 2 rounds).
// EPI 1: +bias + embed[seq[row]] -> f32.
// ---------------------------------------------------------------------------
template<int EPI>
__global__ __launch_bounds__(256, 3)
void gemmk(const ushort_t* __restrict__ Ah, const ushort_t* __restrict__ Al,
           const ushort_t* __restrict__ Bh, const ushort_t* __restrict__ Bl,
           const float* __restrict__ bias,
           const int* __restrict__ seq, const float* __restrict__ embed,
           ushort_t* __restrict__ Oh, ushort_t* __restrict__ Ol,
           float* __restrict__ Of, int N, int K)
{
  __shared__ __align__(16) ushort_t lds[16384];   // 32 KB
  const int tid = threadIdx.x;
  const int numN = N >> 7;
  int bid = blockIdx.x;
  {  // XCD-aware swizzle (grids are multiples of 8)
    const int chunk = gridDim.x >> 3;
    bid = (bid & 7) * chunk + (bid >> 3);
  }
  const int m0 = (bid / numN) << 7;
  const int n0 = (bid % numN) << 7;
  const int wid = tid >> 6, lane = tid & 63;
  const int wm = wid >> 1, wn = wid & 1;
  const int l16 = lane & 15, lkb = lane >> 4;

  const int tpt = K >> 5;       // real-K tiles per third
  const int NT  = 3 * tpt;      // virtual tiles

  // staging: tile = 512 chunks of 16B; thread covers LDS chunks tid, tid+256.
  // LDS chunk j: pair p=j>>3, c=j&7 -> global chunk g=c^(p&7) -> row 2p+(g>>2),
  // col (g&3)*8.
  int offA[2], offB[2];
#pragma unroll
  for (int j2 = 0; j2 < 2; ++j2) {
    const int j = tid + j2 * 256;
    const int p = j >> 3, c = j & 7, g = c ^ (p & 7);
    const int row = 2 * p + (g >> 2), col = (g & 3) * 8;
    offA[j2] = (m0 + row) * K + col;
    offB[j2] = (n0 + row) * K + col;
  }

  auto stage = [&](int ts, int buf) {
    const int th = (ts >= tpt) + (ts >= 2 * tpt);
    const int kb = (ts - th * tpt) << 5;
    const ushort_t* pa = ((th == 1) ? Al : Ah) + kb;
    const ushort_t* pb = ((th == 2) ? Bl : Bh) + kb;
    ushort_t* d = lds + buf * 8192 + wid * 512;
    gl16(pa + offA[0], d);
    gl16(pa + offA[1], d + 2048);
    gl16(pb + offB[0], d + 4096);
    gl16(pb + offB[1], d + 4096 + 2048);
  };

  // fragment addressing (u16 units): pair stride 64, m-frag stride 8 pairs=512
  const int cc = (((l16 & 1) << 2) | lkb) ^ (l16 >> 1);
  const int aB = (wm * 32 + (l16 >> 1)) * 64 + cc * 8;
  const int bB = 4096 + (wn * 32 + (l16 >> 1)) * 64 + cc * 8;

  bf16x8 fa[4], fb[4];
  f32x4 acc[4][4];
#pragma unroll
  for (int m = 0; m < 4; ++m)
#pragma unroll
    for (int n = 0; n < 4; ++n) acc[m][n] = (f32x4){0.f, 0.f, 0.f, 0.f};

  auto ldfrag = [&](int buf) {
    const ushort_t* b0 = lds + buf * 8192;
#pragma unroll
    for (int m = 0; m < 4; ++m)
      fa[m] = *(const bf16x8*)(b0 + aB + m * 512);
#pragma unroll
    for (int nf = 0; nf < 4; ++nf)
      fb[nf] = *(const bf16x8*)(b0 + bB + nf * 512);
  };
  auto mfma16 = [&]() {
    __builtin_amdgcn_s_setprio(1);
#pragma unroll
    for (int m = 0; m < 4; ++m)
#pragma unroll
      for (int nf = 0; nf < 4; ++nf)
        acc[m][nf] = __builtin_amdgcn_mfma_f32_16x16x32_bf16(
            fa[m], fb[nf], acc[m][nf], 0, 0, 0);
    __builtin_amdgcn_s_setprio(0);
  };

  // prologue: tile 0 staged + verified
  stage(0, 0);
  VMC0; BARRIER; SBAR;

  for (int t = 0; t < NT; ++t) {
    const int buf = t & 1;
    ldfrag(buf);
    if (t + 1 < NT) stage(t + 1, buf ^ 1);
    LGKM0; SBAR;
    mfma16();
    if (t + 1 < NT) { VMC0; BARRIER; SBAR; }
  }

  // epilogue: wave tile 64x64 at rows m0+wm*64, cols n0+wn*64.
  // C/D frag: col=l16 (n), row=lkb*4+ii (m)
  if (EPI == 0) {
    BARRIER;                                     // all LDS reads done
    unsigned* pw = (unsigned*)lds + wid * 2048;  // 8 KB per wave
    float bv[4];
#pragma unroll
    for (int nf = 0; nf < 4; ++nf) bv[nf] = bias[n0 + wn * 64 + nf * 16 + l16];
#pragma unroll
    for (int half = 0; half < 2; ++half) {
#pragma unroll
      for (int m = 0; m < 2; ++m) {
        const int mg = half * 2 + m;
#pragma unroll
        for (int nf = 0; nf < 4; ++nf)
#pragma unroll
          for (int ii = 0; ii < 4; ++ii) {
            float v = fmaxf(acc[mg][nf][ii] + bv[nf], 0.f);
            const ushort_t h = f2bf(v);
            const ushort_t l = f2bf(v - bf2f(h));
            const int row = m * 16 + lkb * 4 + ii;
            pw[row * 64 + nf * 16 + l16] = ((unsigned)h << 16) | l;
          }
      }
#pragma unroll
      for (int p = 0; p < 8; ++p) {
        const int idx = p * 256 + lane * 4;
        const int row = idx >> 6, col = idx & 63;
        const uint4 w = *(const uint4*)(pw + idx);
        ushort4 hs, ls;
        hs.x = (ushort_t)(w.x >> 16); ls.x = (ushort_t)(w.x & 0xffffu);
        hs.y = (ushort_t)(w.y >> 16); ls.y = (ushort_t)(w.y & 0xffffu);
        hs.z = (ushort_t)(w.z >> 16); ls.z = (ushort_t)(w.z & 0xffffu);
        hs.w = (ushort_t)(w.w >> 16); ls.w = (ushort_t)(w.w & 0xffffu);
        const size_t go = (size_t)(m0 + wm * 64 + half * 32 + row) * N
                          + (n0 + wn * 64 + col);
        *(ushort4*)(Oh + go) = hs;
        *(ushort4*)(Ol + go) = ls;
      }
    }
  } else {
#pragma unroll
    for (int nf = 0; nf < 4; ++nf) {
      const int col = n0 + wn * 64 + nf * 16 + l16;
      const float bvv = bias[col];
#pragma unroll
      for (int m = 0; m < 4; ++m) {
        const int rbase = m0 + wm * 64 + m * 16 + lkb * 4;
#pragma unroll
        for (int ii = 0; ii < 4; ++ii) {
          const int row = rbase + ii;
          float v = acc[m][nf][ii] + bvv;
          v += embed[(size_t)seq[row] * 512 + col];
          Of[(size_t)row * N + col] = v;
        }
      }
    }
  }
}

// in-place LayerNorm + fused gate score + L2 norm; one wave per 512-elem row
__global__ __launch_bounds__(256)
void lnscore_k(float* __restrict__ x, const float* __restrict__ g,
               const float* __restrict__ bt, const float* __restrict__ wg_w,
               const float* __restrict__ wg_b, float* __restrict__ scores,
               float* __restrict__ norms)
{
  const int wid = threadIdx.x >> 6, lane = threadIdx.x & 63;
  const int row = blockIdx.x * 4 + wid;
  float* xr = x + (size_t)row * 512;
  const float4 v0 = *(const float4*)(xr + lane*4);
  const float4 v1 = *(const float4*)(xr + 256 + lane*4);
  float s = v0.x+v0.y+v0.z+v0.w + v1.x+v1.y+v1.z+v1.w;
  s = wsum64(s);
  const float mu = s * (1.f/512.f);
  float ss = (v0.x-mu)*(v0.x-mu) + (v0.y-mu)*(v0.y-mu)
           + (v0.z-mu)*(v0.z-mu) + (v0.w-mu)*(v0.w-mu)
           + (v1.x-mu)*(v1.x-mu) + (v1.y-mu)*(v1.y-mu)
           + (v1.z-mu)*(v1.z-mu) + (v1.w-mu)*(v1.w-mu);
  ss = wsum64(ss);
  const float inv = 1.f / sqrtf(ss * (1.f/512.f) + 1e-5f);
  const float4 g0 = *(const float4*)(g + lane*4);
  const float4 g1 = *(const float4*)(g + 256 + lane*4);
  const float4 c0 = *(const float4*)(bt + lane*4);
  const float4 c1 = *(const float4*)(bt + 256 + lane*4);
  float4 o0, o1;
  o0.x = (v0.x-mu)*inv*g0.x + c0.x;  o0.y = (v0.y-mu)*inv*g0.y + c0.y;
  o0.z = (v0.z-mu)*inv*g0.z + c0.z;  o0.w = (v0.w-mu)*inv*g0.w + c0.w;
  o1.x = (v1.x-mu)*inv*g1.x + c1.x;  o1.y = (v1.y-mu)*inv*g1.y + c1.y;
  o1.z = (v1.z-mu)*inv*g1.z + c1.z;  o1.w = (v1.w-mu)*inv*g1.w + c1.w;
  *(float4*)(xr + lane*4) = o0;
  *(float4*)(xr + 256 + lane*4) = o1;

  const float4 q0 = *(const float4*)(wg_w + lane*4);
  const float4 q1 = *(const float4*)(wg_w + 256 + lane*4);
  float d = o0.x*q0.x + o0.y*q0.y + o0.z*q0.z + o0.w*q0.w
          + o1.x*q1.x + o1.y*q1.y + o1.z*q1.z + o1.w*q1.w;
  float n2 = o0.x*o0.x + o0.y*o0.y + o0.z*o0.z + o0.w*o0.w
           + o1.x*o1.x + o1.y*o1.y + o1.z*o1.z + o1.w*o1.w;
  d = wsum64(d); n2 = wsum64(n2);
  const int b = row >> 10, t = row & 1023;
  if (lane == 0 && t < 1021) {
    scores[b * 1021 + t] = d + wg_b[0];
    norms[b * 1021 + t] = sqrtf(n2);
  }
}

// ---------------------------------------------------------------------------
// Greedy score-ranked selection with cosine dedup; one block per batch row.
// ---------------------------------------------------------------------------
__global__ __launch_bounds__(256, 1)
void select_k(const float* __restrict__ hidden, const float* __restrict__ scores,
              const float* __restrict__ norms, int* __restrict__ selidx_g,
              int* __restrict__ selcnt_g)
{
  __shared__ __align__(16) ushort_t allH[128 * 520];     // 133120 B (keys alias)
  __shared__ ushort_t simS[64 * 128];
  __shared__ ushort_t sortedIdx[1024];
  __shared__ ushort_t selT[64];
  __shared__ ushort_t newPos[64];
  __shared__ int s_count, s_nacc;

  const int b = blockIdx.x, tid = threadIdx.x;
  const int wid = tid >> 6, lane = tid & 63;
  const int l16 = lane & 15, lkb = lane >> 4;

  unsigned long long* keys = (unsigned long long*)allH;
  for (int i = tid; i < 1024; i += 256) {
    const float s = (i < 1021) ? scores[b * 1021 + i] : -INFINITY;
    const unsigned u = __float_as_uint(s);
    const unsigned ms = (u & 0x80000000u) ? ~u : (u | 0x80000000u);
    keys[i] = ((unsigned long long)(~ms) << 32) | (unsigned)i;
  }
  __syncthreads();
  for (int k = 2; k <= 1024; k <<= 1) {
    for (int j = k >> 1; j > 0; j >>= 1) {
      for (int i = tid; i < 1024; i += 256) {
        const int ixj = i ^ j;
        if (ixj > i) {
          const unsigned long long a = keys[i], c = keys[ixj];
          const bool up = ((i & k) == 0);
          if ((a > c) == up) { keys[i] = c; keys[ixj] = a; }
        }
      }
      __syncthreads();
    }
  }
  for (int i = tid; i < 1024; i += 256)
    sortedIdx[i] = (ushort_t)(keys[i] & 0xffffu);
  if (tid == 0) s_count = 0;
  __syncthreads();

  int p = 0;
  while (true) {
    const int count = s_count;
    if (count >= 64 || p >= 1021) break;
    const int C = min(64, 1021 - p);

    {
      const int r = tid >> 2;
      const int seg = (tid & 3) * 128;
      if (r < C) {
        const int t = sortedIdx[p + r];
        const float rn = 1.f / fmaxf(norms[b * 1021 + t], 1e-12f);
        const float* src = hidden + ((size_t)b * 1024 + t) * 512 + seg;
        ushort_t* dst = allH + (64 + r) * 520 + seg;
#pragma unroll
        for (int u0 = 0; u0 < 128; u0 += 8) {
          const float4 x = *(const float4*)(src + u0);
          const float4 y = *(const float4*)(src + u0 + 4);
          u16x8 o;
          o[0] = f2bf(x.x * rn); o[1] = f2bf(x.y * rn);
          o[2] = f2bf(x.z * rn); o[3] = f2bf(x.w * rn);
          o[4] = f2bf(y.x * rn); o[5] = f2bf(y.y * rn);
          o[6] = f2bf(y.z * rn); o[7] = f2bf(y.w * rn);
          *(u16x8*)(dst + u0) = o;
        }
      }
    }
    __syncthreads();

    {
      f32x4 acc[8];
#pragma unroll
      for (int t = 0; t < 8; ++t) acc[t] = (f32x4){0.f, 0.f, 0.f, 0.f};
      const ushort_t* Abase = allH + (64 + (wid << 4) + l16) * 520;
#pragma unroll
      for (int ks = 0; ks < 16; ++ks) {
        const bf16x8 a = *(const bf16x8*)(Abase + ks * 32 + lkb * 8);
#pragma unroll
        for (int t = 0; t < 8; ++t) {
          const bf16x8 bb = *(const bf16x8*)(allH + ((t << 4) + l16) * 520 + ks * 32 + lkb * 8);
          acc[t] = __builtin_amdgcn_mfma_f32_16x16x32_bf16(a, bb, acc[t], 0, 0, 0);
        }
      }
#pragma unroll
      for (int t = 0; t < 8; ++t)
#pragma unroll
        for (int ii = 0; ii < 4; ++ii) {
          const int ri = (wid << 4) + lkb * 4 + ii;
          simS[ri * 128 + (t << 4) + l16] = f2bf(acc[t][ii]);
        }
    }
    __syncthreads();

    if (wid == 0) {
      unsigned long long accMask = 0ull;
      int nacc = 0;
      for (int i = 0; i < C; ++i) {
        float v = -INFINITY;
        if (lane < count) v = bf2f(simS[i * 128 + lane]);
        if ((accMask >> lane) & 1ull) v = fmaxf(v, bf2f(simS[i * 128 + 64 + lane]));
#pragma unroll
        for (int off = 32; off > 0; off >>= 1) v = fmaxf(v, __shfl_xor(v, off, 64));
        const int total = count + nacc;
        const bool ok = (total == 0) || (v <= 0.8f);
        if (total < 64 && ok) {
          if (lane == 0) { selT[total] = sortedIdx[p + i]; newPos[nacc] = (ushort_t)i; }
          accMask |= (1ull << i);
          ++nacc;
          if (total + 1 == 64) break;
        }
      }
      if (lane == 0) { s_nacc = nacc; s_count = count + nacc; }
    }
    __syncthreads();

    {
      const int nacc = s_nacc;
      for (int a = wid; a < nacc; a += 4) {
        const int srcrow = 64 + (int)newPos[a];
        const int dstrow = count + a;
        const u16x8 val = *(const u16x8*)(allH + srcrow * 520 + lane * 8);
        *(u16x8*)(allH + dstrow * 520 + lane * 8) = val;
      }
    }
    p += C;
    __syncthreads();
  }

  __syncthreads();
  if (tid < 64) selidx_g[b * 64 + tid] = (tid < s_count) ? (int)selT[tid] : 0;
  if (tid == 0) selcnt_g[b] = s_count;
}

// q = hidden[:, T-2, :] @ q_w^T + q_b ; one wave per output element
__global__ __launch_bounds__(256)
void q_k(const float* __restrict__ hidden, const float* __restrict__ q_w,
         const float* __restrict__ q_b, float* __restrict__ qv)
{
  const int wid = threadIdx.x >> 6, lane = threadIdx.x & 63;
  const int o = blockIdx.x * 4 + wid;
  const int b = o >> 9, n = o & 511;
  const float* hr = hidden + ((size_t)b*1024 + 1022) * 512;
  const float* wr = q_w + (size_t)n * 512;
  const float4 h0 = *(const float4*)(hr + lane*4);
  const float4 h1 = *(const float4*)(hr + 256 + lane*4);
  const float4 w0 = *(const float4*)(wr + lane*4);
  const float4 w1 = *(const float4*)(wr + 256 + lane*4);
  float d = h0.x*w0.x + h0.y*w0.y + h0.z*w0.z + h0.w*w0.w
          + h1.x*w1.x + h1.y*w1.y + h1.z*w1.z + h1.w*w1.w;
  d = wsum64(d);
  if (lane == 0) qv[o] = d + q_b[n];
}

// masked softmax attention over selected memory; one block per batch
__global__ __launch_bounds__(256)
void attn_k(const float* __restrict__ hidden, const float* __restrict__ qv,
            const int* __restrict__ selidx_g, const int* __restrict__ selcnt_g,
            float* __restrict__ ctx)
{
  const int b = blockIdx.x, tid = threadIdx.x;
  const int wid = tid >> 6, lane = tid & 63;
  __shared__ float qs[512];
  __shared__ int sidx[64];
  __shared__ float sv[64];
  __shared__ float av[64];
  const int count = selcnt_g[b];
  for (int i = tid; i < 512; i += 256) qs[i] = qv[b*512 + i];
  if (tid < 64) sidx[tid] = selidx_g[b*64 + tid];
  __syncthreads();
  for (int m = wid; m < 64; m += 4) {
    float sval = -1e9f;
    if (m < count) {
      const float* hr = hidden + ((size_t)b*1024 + sidx[m]) * 512;
      const float4 a0 = *(const float4*)(hr + lane*4);
      const float4 a1 = *(const float4*)(hr + 256 + lane*4);
      const float4 q0 = *(const float4*)(&qs[lane*4]);
      const float4 q1 = *(const float4*)(&qs[256 + lane*4]);
      float d = a0.x*q0.x + a0.y*q0.y + a0.z*q0.z + a0.w*q0.w
              + a1.x*q1.x + a1.y*q1.y + a1.z*q1.z + a1.w*q1.w;
      d = wsum64(d);
      sval = d;
    }
    if (lane == 0) sv[m] = sval;
  }
  __syncthreads();
  if (tid < 64) {
    const float v = sv[tid];
    float mx = v;
#pragma unroll
    for (int off = 32; off > 0; off >>= 1) mx = fmaxf(mx, __shfl_xor(mx, off, 64));
    const float e = expf(v - mx);
    float ssum = e;
#pragma unroll
    for (int off = 32; off > 0; off >>= 1) ssum += __shfl_xor(ssum, off, 64);
    av[tid] = e / ssum;
  }
  __syncthreads();
  for (int n = tid; n < 512; n += 256) {
    float a = 0.f;
    for (int m = 0; m < count; ++m)
      a += av[m] * hidden[((size_t)b*1024 + sidx[m]) * 512 + n];
    ctx[b*512 + n] = a;
  }
}

// ---------------------------------------------------------------------------
// out = ctx @ out_w^T + out_b via streaming split-bf16 MFMA (R7, kept).
// ---------------------------------------------------------------------------
__global__ __launch_bounds__(256, 2)
void out_k(const float* __restrict__ ctx, const float* __restrict__ out_w,
           const float* __restrict__ out_b, float* __restrict__ out)
{
  __shared__ __align__(16) ushort_t ctxH[32 * 520];
  __shared__ __align__(16) ushort_t ctxL[32 * 520];
  const int tid = threadIdx.x;
  const int wid = tid >> 6, lane = tid & 63;
  const int l16 = lane & 15, lkb = lane >> 4;

  {
    const int row = tid >> 3;
    const int c0 = (tid & 7) * 64;
    const float* src = ctx + row * 512 + c0;
    ushort_t* dh = ctxH + row * 520 + c0;
    ushort_t* dl = ctxL + row * 520 + c0;
#pragma unroll
    for (int u0 = 0; u0 < 64; u0 += 8) {
      const float4 a = *(const float4*)(src + u0);
      const float4 b = *(const float4*)(src + u0 + 4);
      u16x8 h, l;
      split8(a, b, h, l);
      *(u16x8*)(dh + u0) = h;
      *(u16x8*)(dl + u0) = l;
    }
  }
  __syncthreads();

  const int v = blockIdx.x * 64 + wid * 16 + l16;
  const float* wr = out_w + (size_t)v * 512 + lkb * 8;
  f32x4 acc0 = (f32x4){0.f, 0.f, 0.f, 0.f};
  f32x4 acc1 = (f32x4){0.f, 0.f, 0.f, 0.f};
#pragma unroll
  for (int ks = 0; ks < 16; ++ks) {
    const float4 wa = *(const float4*)(wr + ks * 32);
    const float4 wb = *(const float4*)(wr + ks * 32 + 4);
    u16x8 wh, wl;
    split8(wa, wb, wh, wl);
    const bf16x8 whb = (bf16x8)wh, wlb = (bf16x8)wl;
    const int co = ks * 32 + lkb * 8;
    const bf16x8 ch0 = *(const bf16x8*)(ctxH + l16 * 520 + co);
    const bf16x8 cl0 = *(const bf16x8*)(ctxL + l16 * 520 + co);
    const bf16x8 ch1 = *(const bf16x8*)(ctxH + (16 + l16) * 520 + co);
    const bf16x8 cl1 = *(const bf16x8*)(ctxL + (16 + l16) * 520 + co);
    acc0 = __builtin_amdgcn_mfma_f32_16x16x32_bf16(ch0, whb, acc0, 0, 0, 0);
    acc0 = __builtin_amdgcn_mfma_f32_16x16x32_bf16(cl0, whb, acc0, 0, 0, 0);
    acc0 = __builtin_amdgcn_mfma_f32_16x16x32_bf16(ch0, wlb, acc0, 0, 0, 0);
    acc1 = __builtin_amdgcn_mfma_f32_16x16x32_bf16(ch1, whb, acc1, 0, 0, 0);
    acc1 = __builtin_amdgcn_mfma_f32_16x16x32_bf16(cl1, whb, acc1, 0, 0, 0);
    acc1 = __builtin_amdgcn_mfma_f32_16x16x32_bf16(ch1, wlb, acc1, 0, 0, 0);
  }
  const float bv = out_b[v];
#pragma unroll
  for (int i = 0; i < 4; ++i) {
    out[(size_t)(lkb * 4 + i) * 32000 + v] = acc0[i] + bv;
    out[(size_t)(16 + lkb * 4 + i) * 32000 + v] = acc1[i] + bv;
  }
}

extern "C" void kernel_launch(void* const* d_in, const int* in_sizes, int n_in,
                              void* d_out, int out_size, void* d_ws, size_t ws_size,
                              hipStream_t stream)
{
  const int*   seq   = (const int*)d_in[0];
  const float* embed = (const float*)d_in[1];
  const float* w1    = (const float*)d_in[2];
  const float* b1    = (const float*)d_in[3];
  const float* w2    = (const float*)d_in[4];
  const float* b2    = (const float*)d_in[5];
  const float* ln_g  = (const float*)d_in[6];
  const float* ln_b  = (const float*)d_in[7];
  const float* wg_w  = (const float*)d_in[8];
  const float* wg_b  = (const float*)d_in[9];
  const float* q_w   = (const float*)d_in[10];
  const float* q_b   = (const float*)d_in[11];
  const float* out_w = (const float*)d_in[12];
  const float* out_b = (const float*)d_in[13];
  float* out = (float*)d_out;

  char* ws = (char*)d_ws;
  size_t off = 0;
  auto alloc = [&](size_t bytes) {
    void* p = ws + off;
    off += (bytes + 255) & ~(size_t)255;
    return p;
  };
  void* xA = alloc((size_t)32768 * 512 * 4);            // 67 MB
  ushort_t* Ahid = (ushort_t*)xA;
  ushort_t* Alid = Ahid + (size_t)32768 * 512;
  float* xbuf = (float*)xA;
  ushort_t* ff1h = (ushort_t*)alloc((size_t)32768 * 1024 * 2);  // 67 MB
  ushort_t* ff1l = (ushort_t*)alloc((size_t)32768 * 1024 * 2);  // 67 MB
  ushort_t* w1h = (ushort_t*)alloc((size_t)1024 * 512 * 2);
  ushort_t* w1l = (ushort_t*)alloc((size_t)1024 * 512 * 2);
  ushort_t* w2h = (ushort_t*)alloc((size_t)512 * 1024 * 2);
  ushort_t* w2l = (ushort_t*)alloc((size_t)512 * 1024 * 2);
  float* scores = (float*)alloc((size_t)32 * 1021 * 4);
  float* norms  = (float*)alloc((size_t)32 * 1021 * 4);
  int*   selidx = (int*)alloc((size_t)32 * 64 * 4);
  int*   selcnt = (int*)alloc((size_t)32 * 4);
  float* qbuf   = (float*)alloc((size_t)32 * 512 * 4);
  float* ctxb   = (float*)alloc((size_t)32 * 512 * 4);

  gather_split<<<8192, 256, 0, stream>>>(seq, embed, Ahid, Alid);
  split_w<<<256, 256, 0, stream>>>(w1, w1h, w1l, 65536);
  split_w<<<256, 256, 0, stream>>>(w2, w2h, w2l, 65536);

  // FF1: relu(h @ w1^T + b1) -> ff1 hi/lo bf16  [32768,1024]
  gemmk<0><<<2048, 256, 0, stream>>>(Ahid, Alid, w1h, w1l, b1,
                                     nullptr, nullptr, ff1h, ff1l, nullptr,
                                     1024, 512);
  // FF2: ff1 @ w2^T + b2 + embed[seq] -> xbuf f32 [32768,512]
  gemmk<1><<<1024, 256, 0, stream>>>(ff1h, ff1l, w2h, w2l, b2,
                                     seq, embed, nullptr, nullptr, xbuf,
                                     512, 1024);
  lnscore_k<<<8192, 256, 0, stream>>>(xbuf, ln_g, ln_b, wg_w, wg_b, scores, norms);
  select_k<<<32, 256, 0, stream>>>(xbuf, scores, norms, selidx, selcnt);
  q_k<<<4096, 256, 0, stream>>>(xbuf, q_w, q_b, qbuf);
  attn_k<<<32, 256, 0, stream>>>(xbuf, qbuf, selidx, selcnt, ctxb);
  out_k<<<500, 256, 0, stream>>>(ctxb, out_w, out_b, out);
}

// Round 10
// 407.931 us; speedup vs baseline: 1.0308x; 1.0308x over previous
//
#include <hip/hip_runtime.h>
#include <math.h>

typedef unsigned short ushort_t;
typedef short bf16x8 __attribute__((ext_vector_type(8)));
typedef unsigned short u16x8 __attribute__((ext_vector_type(8)));
typedef float f32x4 __attribute__((ext_vector_type(4)));

__device__ __forceinline__ float wsum64(float v) {
#pragma unroll
  for (int off = 32; off > 0; off >>= 1) v += __shfl_xor(v, off, 64);
  return v;
}

__device__ __forceinline__ ushort_t f2bf(float x) {   // RNE f32->bf16
  unsigned u = __float_as_uint(x);
  return (ushort_t)((u + 0x7fffu + ((u >> 16) & 1u)) >> 16);
}
__device__ __forceinline__ float bf2f(ushort_t h) {
  return __uint_as_float(((unsigned)h) << 16);
}

__device__ __forceinline__ void split8(const float4 a, const float4 b,
                                       u16x8& h, u16x8& l) {
  h[0]=f2bf(a.x); l[0]=f2bf(a.x-bf2f(h[0]));
  h[1]=f2bf(a.y); l[1]=f2bf(a.y-bf2f(h[1]));
  h[2]=f2bf(a.z); l[2]=f2bf(a.z-bf2f(h[2]));
  h[3]=f2bf(a.w); l[3]=f2bf(a.w-bf2f(h[3]));
  h[4]=f2bf(b.x); l[4]=f2bf(b.x-bf2f(h[4]));
  h[5]=f2bf(b.y); l[5]=f2bf(b.y-bf2f(h[5]));
  h[6]=f2bf(b.z); l[6]=f2bf(b.z-bf2f(h[6]));
  h[7]=f2bf(b.w); l[7]=f2bf(b.w-bf2f(h[7]));
}

// async global(per-lane) -> LDS(wave-uniform base + lane*16B), 16B per lane
__device__ __forceinline__ void gl16(const void* g, const void* l) {
  __builtin_amdgcn_global_load_lds(
      (const __attribute__((address_space(1))) unsigned int*)g,
      (__attribute__((address_space(3))) unsigned int*)l, 16, 0, 0);
}

#define SBAR __builtin_amdgcn_sched_barrier(0)
#define BARRIER __builtin_amdgcn_s_barrier()
#define LGKM0 asm volatile("s_waitcnt lgkmcnt(0)" ::: "memory")
#define VMC4 asm volatile("s_waitcnt vmcnt(4)" ::: "memory")
#define VMC0 asm volatile("s_waitcnt vmcnt(0)" ::: "memory")

// ---------------------------------------------------------------------------
// gather-split: Ah/Al[row][512] bf16 hi/lo of embed[seq[row]]
// ---------------------------------------------------------------------------
__global__ __launch_bounds__(256)
void gather_split(const int* __restrict__ seq, const float* __restrict__ embed,
                  ushort_t* __restrict__ Ah, ushort_t* __restrict__ Al)
{
  const int wid = threadIdx.x >> 6, lane = threadIdx.x & 63;
  const int row = blockIdx.x * 4 + wid;
  const float* src = embed + (size_t)seq[row] * 512 + lane * 8;
  const float4 a = *(const float4*)src;
  const float4 b = *(const float4*)(src + 4);
  u16x8 h, l;
  split8(a, b, h, l);
  *(u16x8*)(Ah + (size_t)row * 512 + lane * 8) = h;
  *(u16x8*)(Al + (size_t)row * 512 + lane * 8) = l;
}

// elementwise weight split (n8 = total_elems/8)
__global__ __launch_bounds__(256)
void split_w(const float* __restrict__ W, ushort_t* __restrict__ Wh,
             ushort_t* __restrict__ Wl, int n8)
{
  const int i = blockIdx.x * 256 + threadIdx.x;
  if (i >= n8) return;
  const float4 a = *(const float4*)(W + (size_t)i * 8);
  const float4 b = *(const float4*)(W + (size_t)i * 8 + 4);
  u16x8 h, l;
  split8(a, b, h, l);
  *(u16x8*)(Wh + (size_t)i * 8) = h;
  *(u16x8*)(Wl + (size_t)i * 8) = l;
}

// ---------------------------------------------------------------------------
// Split-bf16 MFMA GEMM as virtual K'=3K bf16 GEMM (A'=[Ah|Al|Ah], B'=[Bh|Bh|Bl]).
// 128x128 tile, 4 waves (2Mx2N), per-wave 64x64 = acc[4][4]. BK=32 virtual.
// LDS 48 KB = 3 stages x (A 8KB + B 8KB) -> 3 blocks/CU (12 waves).
// T4 counted-vmcnt pipeline (fix for R9's drain-per-tile): tile t in buf t%3;
// at iter t issue stage(t+2 -> buf (t+2)%3 == (t-1)%3, whose readers passed
// the end-of-(t-1) barrier). Tile boundary waits vmcnt(4): queue = {t+1:4,
// t+2:4} -> retires exactly tile t+1; NEVER drains to 0 in steady state.
// Tail (t = NT-2): only t+1's 4 loads outstanding -> vmcnt(0).
// LDS layout per matrix tile (128 rows x 32 cols bf16): row-PAIRS of 128 B
// (8 chunks x 16 B); LDS chunk c of pair p holds global chunk g = c ^ (p&7)
// (g -> row 2p+(g>>2), col (g&3)*8): uniform 2-way banked reads (free, m136),
// linear gl16 dests + pre-swizzled sources (m173). Measured 0 conflicts (R9).
// EPI 0: +bias, relu -> Oh/Ol bf16 hi/lo (8KB-per-wave LDS bounce, 2 rounds).
// EPI 1: +bias + embed[seq[row]] -> f32.
// ---------------------------------------------------------------------------
template<int EPI>
__global__ __launch_bounds__(256, 3)
void gemmk(const ushort_t* __restrict__ Ah, const ushort_t* __restrict__ Al,
           const ushort_t* __restrict__ Bh, const ushort_t* __restrict__ Bl,
           const float* __restrict__ bias,
           const int* __restrict__ seq, const float* __restrict__ embed,
           ushort_t* __restrict__ Oh, ushort_t* __restrict__ Ol,
           float* __restrict__ Of, int N, int K)
{
  __shared__ __align__(16) ushort_t lds[24576];   // 48 KB = 3 stages x 16 KB
  const int tid = threadIdx.x;
  const int numN = N >> 7;
  int bid = blockIdx.x;
  {  // XCD-aware swizzle (grids are multiples of 8)
    const int chunk = gridDim.x >> 3;
    bid = (bid & 7) * chunk + (bid >> 3);
  }
  const int m0 = (bid / numN) << 7;
  const int n0 = (bid % numN) << 7;
  const int wid = tid >> 6, lane = tid & 63;
  const int wm = wid >> 1, wn = wid & 1;
  const int l16 = lane & 15, lkb = lane >> 4;

  const int tpt = K >> 5;       // real-K tiles per third
  const int NT  = 3 * tpt;      // virtual tiles

  // staging: tile = 512 chunks of 16B; thread covers LDS chunks tid, tid+256.
  // LDS chunk j: pair p=j>>3, c=j&7 -> global chunk g=c^(p&7) -> row 2p+(g>>2),
  // col (g&3)*8.
  int offA[2], offB[2];
#pragma unroll
  for (int j2 = 0; j2 < 2; ++j2) {
    const int j = tid + j2 * 256;
    const int p = j >> 3, c = j & 7, g = c ^ (p & 7);
    const int row = 2 * p + (g >> 2), col = (g & 3) * 8;
    offA[j2] = (m0 + row) * K + col;
    offB[j2] = (n0 + row) * K + col;
  }

  auto stage = [&](int ts, int buf) {
    const int th = (ts >= tpt) + (ts >= 2 * tpt);
    const int kb = (ts - th * tpt) << 5;
    const ushort_t* pa = ((th == 1) ? Al : Ah) + kb;
    const ushort_t* pb = ((th == 2) ? Bl : Bh) + kb;
    ushort_t* d = lds + buf * 8192 + wid * 512;
    gl16(pa + offA[0], d);
    gl16(pa + offA[1], d + 2048);
    gl16(pb + offB[0], d + 4096);
    gl16(pb + offB[1], d + 4096 + 2048);
  };

  // fragment addressing (u16 units): pair stride 64, m-frag stride 8 pairs=512
  const int cc = (((l16 & 1) << 2) | lkb) ^ (l16 >> 1);
  const int aB = (wm * 32 + (l16 >> 1)) * 64 + cc * 8;
  const int bB = 4096 + (wn * 32 + (l16 >> 1)) * 64 + cc * 8;

  bf16x8 fa[4], fb[4];
  f32x4 acc[4][4];
#pragma unroll
  for (int m = 0; m < 4; ++m)
#pragma unroll
    for (int n = 0; n < 4; ++n) acc[m][n] = (f32x4){0.f, 0.f, 0.f, 0.f};

  auto ldfrag = [&](int buf) {
    const ushort_t* b0 = lds + buf * 8192;
#pragma unroll
    for (int m = 0; m < 4; ++m)
      fa[m] = *(const bf16x8*)(b0 + aB + m * 512);
#pragma unroll
    for (int nf = 0; nf < 4; ++nf)
      fb[nf] = *(const bf16x8*)(b0 + bB + nf * 512);
  };
  auto mfma16 = [&]() {
    __builtin_amdgcn_s_setprio(1);
#pragma unroll
    for (int m = 0; m < 4; ++m)
#pragma unroll
      for (int nf = 0; nf < 4; ++nf)
        acc[m][nf] = __builtin_amdgcn_mfma_f32_16x16x32_bf16(
            fa[m], fb[nf], acc[m][nf], 0, 0, 0);
    __builtin_amdgcn_s_setprio(0);
  };

  // prologue: stage tiles 0,1; verify tile 0 (8 outstanding -> wait to 4)
  stage(0, 0); stage(1, 1);
  VMC4; BARRIER; SBAR;

  int buf = 0;
  for (int t = 0; t < NT; ++t) {
    ldfrag(buf);                                      // reads tile t (verified)
    const int b2 = (buf + 2 >= 3) ? (buf - 1) : (buf + 2);
    if (t + 2 < NT) stage(t + 2, b2);                 // writes buf (t-1)%3: safe
    LGKM0; SBAR;
    mfma16();
    if (t + 1 < NT) {
      if (t + 2 < NT) { VMC4; }                       // retire tile t+1 exactly
      else            { VMC0; }                       // tail: only 4 outstanding
      BARRIER; SBAR;
    }
    buf = (buf + 1 >= 3) ? 0 : buf + 1;
  }

  // epilogue: wave tile 64x64 at rows m0+wm*64, cols n0+wn*64.
  // C/D frag: col=l16 (n), row=lkb*4+ii (m)
  if (EPI == 0) {
    BARRIER;                                     // all LDS reads done
    unsigned* pw = (unsigned*)lds + wid * 2048;  // 8 KB per wave
    float bv[4];
#pragma unroll
    for (int nf = 0; nf < 4; ++nf) bv[nf] = bias[n0 + wn * 64 + nf * 16 + l16];
#pragma unroll
    for (int half = 0; half < 2; ++half) {
#pragma unroll
      for (int m = 0; m < 2; ++m) {
        const int mg = half * 2 + m;
#pragma unroll
        for (int nf = 0; nf < 4; ++nf)
#pragma unroll
          for (int ii = 0; ii < 4; ++ii) {
            float v = fmaxf(acc[mg][nf][ii] + bv[nf], 0.f);
            const ushort_t h = f2bf(v);
            const ushort_t l = f2bf(v - bf2f(h));
            const int row = m * 16 + lkb * 4 + ii;
            pw[row * 64 + nf * 16 + l16] = ((unsigned)h << 16) | l;
          }
      }
#pragma unroll
      for (int p = 0; p < 8; ++p) {
        const int idx = p * 256 + lane * 4;
        const int row = idx >> 6, col = idx & 63;
        const uint4 w = *(const uint4*)(pw + idx);
        ushort4 hs, ls;
        hs.x = (ushort_t)(w.x >> 16); ls.x = (ushort_t)(w.x & 0xffffu);
        hs.y = (ushort_t)(w.y >> 16); ls.y = (ushort_t)(w.y & 0xffffu);
        hs.z = (ushort_t)(w.z >> 16); ls.z = (ushort_t)(w.z & 0xffffu);
        hs.w = (ushort_t)(w.w >> 16); ls.w = (ushort_t)(w.w & 0xffffu);
        const size_t go = (size_t)(m0 + wm * 64 + half * 32 + row) * N
                          + (n0 + wn * 64 + col);
        *(ushort4*)(Oh + go) = hs;
        *(ushort4*)(Ol + go) = ls;
      }
    }
  } else {
#pragma unroll
    for (int nf = 0; nf < 4; ++nf) {
      const int col = n0 + wn * 64 + nf * 16 + l16;
      const float bvv = bias[col];
#pragma unroll
      for (int m = 0; m < 4; ++m) {
        const int rbase = m0 + wm * 64 + m * 16 + lkb * 4;
#pragma unroll
        for (int ii = 0; ii < 4; ++ii) {
          const int row = rbase + ii;
          float v = acc[m][nf][ii] + bvv;
          v += embed[(size_t)seq[row] * 512 + col];
          Of[(size_t)row * N + col] = v;
        }
      }
    }
  }
}

// in-place LayerNorm + fused gate score + L2 norm; one wave per 512-elem row
__global__ __launch_bounds__(256)
void lnscore_k(float* __restrict__ x, const float* __restrict__ g,
               const float* __restrict__ bt, const float* __restrict__ wg_w,
               const float* __restrict__ wg_b, float* __restrict__ scores,
               float* __restrict__ norms)
{
  const int wid = threadIdx.x >> 6, lane = threadIdx.x & 63;
  const int row = blockIdx.x * 4 + wid;
  float* xr = x + (size_t)row * 512;
  const float4 v0 = *(const float4*)(xr + lane*4);
  const float4 v1 = *(const float4*)(xr + 256 + lane*4);
  float s = v0.x+v0.y+v0.z+v0.w + v1.x+v1.y+v1.z+v1.w;
  s = wsum64(s);
  const float mu = s * (1.f/512.f);
  float ss = (v0.x-mu)*(v0.x-mu) + (v0.y-mu)*(v0.y-mu)
           + (v0.z-mu)*(v0.z-mu) + (v0.w-mu)*(v0.w-mu)
           + (v1.x-mu)*(v1.x-mu) + (v1.y-mu)*(v1.y-mu)
           + (v1.z-mu)*(v1.z-mu) + (v1.w-mu)*(v1.w-mu);
  ss = wsum64(ss);
  const float inv = 1.f / sqrtf(ss * (1.f/512.f) + 1e-5f);
  const float4 g0 = *(const float4*)(g + lane*4);
  const float4 g1 = *(const float4*)(g + 256 + lane*4);
  const float4 c0 = *(const float4*)(bt + lane*4);
  const float4 c1 = *(const float4*)(bt + 256 + lane*4);
  float4 o0, o1;
  o0.x = (v0.x-mu)*inv*g0.x + c0.x;  o0.y = (v0.y-mu)*inv*g0.y + c0.y;
  o0.z = (v0.z-mu)*inv*g0.z + c0.z;  o0.w = (v0.w-mu)*inv*g0.w + c0.w;
  o1.x = (v1.x-mu)*inv*g1.x + c1.x;  o1.y = (v1.y-mu)*inv*g1.y + c1.y;
  o1.z = (v1.z-mu)*inv*g1.z + c1.z;  o1.w = (v1.w-mu)*inv*g1.w + c1.w;
  *(float4*)(xr + lane*4) = o0;
  *(float4*)(xr + 256 + lane*4) = o1;

  const float4 q0 = *(const float4*)(wg_w + lane*4);
  const float4 q1 = *(const float4*)(wg_w + 256 + lane*4);
  float d = o0.x*q0.x + o0.y*q0.y + o0.z*q0.z + o0.w*q0.w
          + o1.x*q1.x + o1.y*q1.y + o1.z*q1.z + o1.w*q1.w;
  float n2 = o0.x*o0.x + o0.y*o0.y + o0.z*o0.z + o0.w*o0.w
           + o1.x*o1.x + o1.y*o1.y + o1.z*o1.z + o1.w*o1.w;
  d = wsum64(d); n2 = wsum64(n2);
  const int b = row >> 10, t = row & 1023;
  if (lane == 0 && t < 1021) {
    scores[b * 1021 + t] = d + wg_b[0];
    norms[b * 1021 + t] = sqrtf(n2);
  }
}

// ---------------------------------------------------------------------------
// Greedy score-ranked selection with cosine dedup; one block per batch row.
// ---------------------------------------------------------------------------
__global__ __launch_bounds__(256, 1)
void select_k(const float* __restrict__ hidden, const float* __restrict__ scores,
              const float* __restrict__ norms, int* __restrict__ selidx_g,
              int* __restrict__ selcnt_g)
{
  __shared__ __align__(16) ushort_t allH[128 * 520];     // 133120 B (keys alias)
  __shared__ ushort_t simS[64 * 128];
  __shared__ ushort_t sortedIdx[1024];
  __shared__ ushort_t selT[64];
  __shared__ ushort_t newPos[64];
  __shared__ int s_count, s_nacc;

  const int b = blockIdx.x, tid = threadIdx.x;
  const int wid = tid >> 6, lane = tid & 63;
  const int l16 = lane & 15, lkb = lane >> 4;

  unsigned long long* keys = (unsigned long long*)allH;
  for (int i = tid; i < 1024; i += 256) {
    const float s = (i < 1021) ? scores[b * 1021 + i] : -INFINITY;
    const unsigned u = __float_as_uint(s);
    const unsigned ms = (u & 0x80000000u) ? ~u : (u | 0x80000000u);
    keys[i] = ((unsigned long long)(~ms) << 32) | (unsigned)i;
  }
  __syncthreads();
  for (int k = 2; k <= 1024; k <<= 1) {
    for (int j = k >> 1; j > 0; j >>= 1) {
      for (int i = tid; i < 1024; i += 256) {
        const int ixj = i ^ j;
        if (ixj > i) {
          const unsigned long long a = keys[i], c = keys[ixj];
          const bool up = ((i & k) == 0);
          if ((a > c) == up) { keys[i] = c; keys[ixj] = a; }
        }
      }
      __syncthreads();
    }
  }
  for (int i = tid; i < 1024; i += 256)
    sortedIdx[i] = (ushort_t)(keys[i] & 0xffffu);
  if (tid == 0) s_count = 0;
  __syncthreads();

  int p = 0;
  while (true) {
    const int count = s_count;
    if (count >= 64 || p >= 1021) break;
    const int C = min(64, 1021 - p);

    {
      const int r = tid >> 2;
      const int seg = (tid & 3) * 128;
      if (r < C) {
        const int t = sortedIdx[p + r];
        const float rn = 1.f / fmaxf(norms[b * 1021 + t], 1e-12f);
        const float* src = hidden + ((size_t)b * 1024 + t) * 512 + seg;
        ushort_t* dst = allH + (64 + r) * 520 + seg;
#pragma unroll
        for (int u0 = 0; u0 < 128; u0 += 8) {
          const float4 x = *(const float4*)(src + u0);
          const float4 y = *(const float4*)(src + u0 + 4);
          u16x8 o;
          o[0] = f2bf(x.x * rn); o[1] = f2bf(x.y * rn);
          o[2] = f2bf(x.z * rn); o[3] = f2bf(x.w * rn);
          o[4] = f2bf(y.x * rn); o[5] = f2bf(y.y * rn);
          o[6] = f2bf(y.z * rn); o[7] = f2bf(y.w * rn);
          *(u16x8*)(dst + u0) = o;
        }
      }
    }
    __syncthreads();

    {
      f32x4 acc[8];
#pragma unroll
      for (int t = 0; t < 8; ++t) acc[t] = (f32x4){0.f, 0.f, 0.f, 0.f};
      const ushort_t* Abase = allH + (64 + (wid << 4) + l16) * 520;
#pragma unroll
      for (int ks = 0; ks < 16; ++ks) {
        const bf16x8 a = *(const bf16x8*)(Abase + ks * 32 + lkb * 8);
#pragma unroll
        for (int t = 0; t < 8; ++t) {
          const bf16x8 bb = *(const bf16x8*)(allH + ((t << 4) + l16) * 520 + ks * 32 + lkb * 8);
          acc[t] = __builtin_amdgcn_mfma_f32_16x16x32_bf16(a, bb, acc[t], 0, 0, 0);
        }
      }
#pragma unroll
      for (int t = 0; t < 8; ++t)
#pragma unroll
        for (int ii = 0; ii < 4; ++ii) {
          const int ri = (wid << 4) + lkb * 4 + ii;
          simS[ri * 128 + (t << 4) + l16] = f2bf(acc[t][ii]);
        }
    }
    __syncthreads();

    if (wid == 0) {
      unsigned long long accMask = 0ull;
      int nacc = 0;
      for (int i = 0; i < C; ++i) {
        float v = -INFINITY;
        if (lane < count) v = bf2f(simS[i * 128 + lane]);
        if ((accMask >> lane) & 1ull) v = fmaxf(v, bf2f(simS[i * 128 + 64 + lane]));
#pragma unroll
        for (int off = 32; off > 0; off >>= 1) v = fmaxf(v, __shfl_xor(v, off, 64));
        const int total = count + nacc;
        const bool ok = (total == 0) || (v <= 0.8f);
        if (total < 64 && ok) {
          if (lane == 0) { selT[total] = sortedIdx[p + i]; newPos[nacc] = (ushort_t)i; }
          accMask |= (1ull << i);
          ++nacc;
          if (total + 1 == 64) break;
        }
      }
      if (lane == 0) { s_nacc = nacc; s_count = count + nacc; }
    }
    __syncthreads();

    {
      const int nacc = s_nacc;
      for (int a = wid; a < nacc; a += 4) {
        const int srcrow = 64 + (int)newPos[a];
        const int dstrow = count + a;
        const u16x8 val = *(const u16x8*)(allH + srcrow * 520 + lane * 8);
        *(u16x8*)(allH + dstrow * 520 + lane * 8) = val;
      }
    }
    p += C;
    __syncthreads();
  }

  __syncthreads();
  if (tid < 64) selidx_g[b * 64 + tid] = (tid < s_count) ? (int)selT[tid] : 0;
  if (tid == 0) selcnt_g[b] = s_count;
}

// q = hidden[:, T-2, :] @ q_w^T + q_b ; one wave per output element
__global__ __launch_bounds__(256)
void q_k(const float* __restrict__ hidden, const float* __restrict__ q_w,
         const float* __restrict__ q_b, float* __restrict__ qv)
{
  const int wid = threadIdx.x >> 6, lane = threadIdx.x & 63;
  const int o = blockIdx.x * 4 + wid;
  const int b = o >> 9, n = o & 511;
  const float* hr = hidden + ((size_t)b*1024 + 1022) * 512;
  const float* wr = q_w + (size_t)n * 512;
  const float4 h0 = *(const float4*)(hr + lane*4);
  const float4 h1 = *(const float4*)(hr + 256 + lane*4);
  const float4 w0 = *(const float4*)(wr + lane*4);
  const float4 w1 = *(const float4*)(wr + 256 + lane*4);
  float d = h0.x*w0.x + h0.y*w0.y + h0.z*w0.z + h0.w*w0.w
          + h1.x*w1.x + h1.y*w1.y + h1.z*w1.z + h1.w*w1.w;
  d = wsum64(d);
  if (lane == 0) qv[o] = d + q_b[n];
}

// masked softmax attention over selected memory; one block per batch
__global__ __launch_bounds__(256)
void attn_k(const float* __restrict__ hidden, const float* __restrict__ qv,
            const int* __restrict__ selidx_g, const int* __restrict__ selcnt_g,
            float* __restrict__ ctx)
{
  const int b = blockIdx.x, tid = threadIdx.x;
  const int wid = tid >> 6, lane = tid & 63;
  __shared__ float qs[512];
  __shared__ int sidx[64];
  __shared__ float sv[64];
  __shared__ float av[64];
  const int count = selcnt_g[b];
  for (int i = tid; i < 512; i += 256) qs[i] = qv[b*512 + i];
  if (tid < 64) sidx[tid] = selidx_g[b*64 + tid];
  __syncthreads();
  for (int m = wid; m < 64; m += 4) {
    float sval = -1e9f;
    if (m < count) {
      const float* hr = hidden + ((size_t)b*1024 + sidx[m]) * 512;
      const float4 a0 = *(const float4*)(hr + lane*4);
      const float4 a1 = *(const float4*)(hr + 256 + lane*4);
      const float4 q0 = *(const float4*)(&qs[lane*4]);
      const float4 q1 = *(const float4*)(&qs[256 + lane*4]);
      float d = a0.x*q0.x + a0.y*q0.y + a0.z*q0.z + a0.w*q0.w
              + a1.x*q1.x + a1.y*q1.y + a1.z*q1.z + a1.w*q1.w;
      d = wsum64(d);
      sval = d;
    }
    if (lane == 0) sv[m] = sval;
  }
  __syncthreads();
  if (tid < 64) {
    const float v = sv[tid];
    float mx = v;
#pragma unroll
    for (int off = 32; off > 0; off >>= 1) mx = fmaxf(mx, __shfl_xor(mx, off, 64));
    const float e = expf(v - mx);
    float ssum = e;
#pragma unroll
    for (int off = 32; off > 0; off >>= 1) ssum += __shfl_xor(ssum, off, 64);
    av[tid] = e / ssum;
  }
  __syncthreads();
  for (int n = tid; n < 512; n += 256) {
    float a = 0.f;
    for (int m = 0; m < count; ++m)
      a += av[m] * hidden[((size_t)b*1024 + sidx[m]) * 512 + n];
    ctx[b*512 + n] = a;
  }
}

// ---------------------------------------------------------------------------
// out = ctx @ out_w^T + out_b via streaming split-bf16 MFMA (R7, kept).
// ---------------------------------------------------------------------------
__global__ __launch_bounds__(256, 2)
void out_k(const float* __restrict__ ctx, const float* __restrict__ out_w,
           const float* __restrict__ out_b, float* __restrict__ out)
{
  __shared__ __align__(16) ushort_t ctxH[32 * 520];
  __shared__ __align__(16) ushort_t ctxL[32 * 520];
  const int tid = threadIdx.x;
  const int wid = tid >> 6, lane = tid & 63;
  const int l16 = lane & 15, lkb = lane >> 4;

  {
    const int row = tid >> 3;
    const int c0 = (tid & 7) * 64;
    const float* src = ctx + row * 512 + c0;
    ushort_t* dh = ctxH + row * 520 + c0;
    ushort_t* dl = ctxL + row * 520 + c0;
#pragma unroll
    for (int u0 = 0; u0 < 64; u0 += 8) {
      const float4 a = *(const float4*)(src + u0);
      const float4 b = *(const float4*)(src + u0 + 4);
      u16x8 h, l;
      split8(a, b, h, l);
      *(u16x8*)(dh + u0) = h;
      *(u16x8*)(dl + u0) = l;
    }
  }
  __syncthreads();

  const int v = blockIdx.x * 64 + wid * 16 + l16;
  const float* wr = out_w + (size_t)v * 512 + lkb * 8;
  f32x4 acc0 = (f32x4){0.f, 0.f, 0.f, 0.f};
  f32x4 acc1 = (f32x4){0.f, 0.f, 0.f, 0.f};
#pragma unroll
  for (int ks = 0; ks < 16; ++ks) {
    const float4 wa = *(const float4*)(wr + ks * 32);
    const float4 wb = *(const float4*)(wr + ks * 32 + 4);
    u16x8 wh, wl;
    split8(wa, wb, wh, wl);
    const bf16x8 whb = (bf16x8)wh, wlb = (bf16x8)wl;
    const int co = ks * 32 + lkb * 8;
    const bf16x8 ch0 = *(const bf16x8*)(ctxH + l16 * 520 + co);
    const bf16x8 cl0 = *(const bf16x8*)(ctxL + l16 * 520 + co);
    const bf16x8 ch1 = *(const bf16x8*)(ctxH + (16 + l16) * 520 + co);
    const bf16x8 cl1 = *(const bf16x8*)(ctxL + (16 + l16) * 520 + co);
    acc0 = __builtin_amdgcn_mfma_f32_16x16x32_bf16(ch0, whb, acc0, 0, 0, 0);
    acc0 = __builtin_amdgcn_mfma_f32_16x16x32_bf16(cl0, whb, acc0, 0, 0, 0);
    acc0 = __builtin_amdgcn_mfma_f32_16x16x32_bf16(ch0, wlb, acc0, 0, 0, 0);
    acc1 = __builtin_amdgcn_mfma_f32_16x16x32_bf16(ch1, whb, acc1, 0, 0, 0);
    acc1 = __builtin_amdgcn_mfma_f32_16x16x32_bf16(cl1, whb, acc1, 0, 0, 0);
    acc1 = __builtin_amdgcn_mfma_f32_16x16x32_bf16(ch1, wlb, acc1, 0, 0, 0);
  }
  const float bv = out_b[v];
#pragma unroll
  for (int i = 0; i < 4; ++i) {
    out[(size_t)(lkb * 4 + i) * 32000 + v] = acc0[i] + bv;
    out[(size_t)(16 + lkb * 4 + i) * 32000 + v] = acc1[i] + bv;
  }
}

extern "C" void kernel_launch(void* const* d_in, const int* in_sizes, int n_in,
                              void* d_out, int out_size, void* d_ws, size_t ws_size,
                              hipStream_t stream)
{
  const int*   seq   = (const int*)d_in[0];
  const float* embed = (const float*)d_in[1];
  const float* w1    = (const float*)d_in[2];
  const float* b1    = (const float*)d_in[3];
  const float* w2    = (const float*)d_in[4];
  const float* b2    = (const float*)d_in[5];
  const float* ln_g  = (const float*)d_in[6];
  const float* ln_b  = (const float*)d_in[7];
  const float* wg_w  = (const float*)d_in[8];
  const float* wg_b  = (const float*)d_in[9];
  const float* q_w   = (const float*)d_in[10];
  const float* q_b   = (const float*)d_in[11];
  const float* out_w = (const float*)d_in[12];
  const float* out_b = (const float*)d_in[13];
  float* out = (float*)d_out;

  char* ws = (char*)d_ws;
  size_t off = 0;
  auto alloc = [&](size_t bytes) {
    void* p = ws + off;
    off += (bytes + 255) & ~(size_t)255;
    return p;
  };
  void* xA = alloc((size_t)32768 * 512 * 4);            // 67 MB
  ushort_t* Ahid = (ushort_t*)xA;
  ushort_t* Alid = Ahid + (size_t)32768 * 512;
  float* xbuf = (float*)xA;
  ushort_t* ff1h = (ushort_t*)alloc((size_t)32768 * 1024 * 2);  // 67 MB
  ushort_t* ff1l = (ushort_t*)alloc((size_t)32768 * 1024 * 2);  // 67 MB
  ushort_t* w1h = (ushort_t*)alloc((size_t)1024 * 512 * 2);
  ushort_t* w1l = (ushort_t*)alloc((size_t)1024 * 512 * 2);
  ushort_t* w2h = (ushort_t*)alloc((size_t)512 * 1024 * 2);
  ushort_t* w2l = (ushort_t*)alloc((size_t)512 * 1024 * 2);
  float* scores = (float*)alloc((size_t)32 * 1021 * 4);
  float* norms  = (float*)alloc((size_t)32 * 1021 * 4);
  int*   selidx = (int*)alloc((size_t)32 * 64 * 4);
  int*   selcnt = (int*)alloc((size_t)32 * 4);
  float* qbuf   = (float*)alloc((size_t)32 * 512 * 4);
  float* ctxb   = (float*)alloc((size_t)32 * 512 * 4);

  gather_split<<<8192, 256, 0, stream>>>(seq, embed, Ahid, Alid);
  split_w<<<256, 256, 0, stream>>>(w1, w1h, w1l, 65536);
  split_w<<<256, 256, 0, stream>>>(w2, w2h, w2l, 65536);

  // FF1: relu(h @ w1^T + b1) -> ff1 hi/lo bf16  [32768,1024]
  gemmk<0><<<2048, 256, 0, stream>>>(Ahid, Alid, w1h, w1l, b1,
                                     nullptr, nullptr, ff1h, ff1l, nullptr,
                                     1024, 512);
  // FF2: ff1 @ w2^T + b2 + embed[seq] -> xbuf f32 [32768,512]
  gemmk<1><<<1024, 256, 0, stream>>>(ff1h, ff1l, w2h, w2l, b2,
                                     seq, embed, nullptr, nullptr, xbuf,
                                     512, 1024);
  lnscore_k<<<8192, 256, 0, stream>>>(xbuf, ln_g, ln_b, wg_w, wg_b, scores, norms);
  select_k<<<32, 256, 0, stream>>>(xbuf, scores, norms, selidx, selcnt);
  q_k<<<4096, 256, 0, stream>>>(xbuf, q_w, q_b, qbuf);
  attn_k<<<32, 256, 0, stream>>>(xbuf, qbuf, selidx, selcnt, ctxb);
  out_k<<<500, 256, 0, stream>>>(ctxb, out_w, out_b, out);
}

// Round 11
// 374.028 us; speedup vs baseline: 1.1243x; 1.0906x over previous
//
#include <hip/hip_runtime.h>
#include <math.h>

typedef unsigned short ushort_t;
typedef short bf16x8 __attribute__((ext_vector_type(8)));
typedef unsigned short u16x8 __attribute__((ext_vector_type(8)));
typedef float f32x4 __attribute__((ext_vector_type(4)));

__device__ __forceinline__ float wsum64(float v) {
#pragma unroll
  for (int off = 32; off > 0; off >>= 1) v += __shfl_xor(v, off, 64);
  return v;
}

__device__ __forceinline__ ushort_t f2bf(float x) {   // RNE f32->bf16
  unsigned u = __float_as_uint(x);
  return (ushort_t)((u + 0x7fffu + ((u >> 16) & 1u)) >> 16);
}
__device__ __forceinline__ float bf2f(ushort_t h) {
  return __uint_as_float(((unsigned)h) << 16);
}

__device__ __forceinline__ void split8(const float4 a, const float4 b,
                                       u16x8& h, u16x8& l) {
  h[0]=f2bf(a.x); l[0]=f2bf(a.x-bf2f(h[0]));
  h[1]=f2bf(a.y); l[1]=f2bf(a.y-bf2f(h[1]));
  h[2]=f2bf(a.z); l[2]=f2bf(a.z-bf2f(h[2]));
  h[3]=f2bf(a.w); l[3]=f2bf(a.w-bf2f(h[3]));
  h[4]=f2bf(b.x); l[4]=f2bf(b.x-bf2f(h[4]));
  h[5]=f2bf(b.y); l[5]=f2bf(b.y-bf2f(h[5]));
  h[6]=f2bf(b.z); l[6]=f2bf(b.z-bf2f(h[6]));
  h[7]=f2bf(b.w); l[7]=f2bf(b.w-bf2f(h[7]));
}

// async global(per-lane) -> LDS(wave-uniform base + lane*16B), 16B per lane
__device__ __forceinline__ void gl16(const void* g, const void* l) {
  __builtin_amdgcn_global_load_lds(
      (const __attribute__((address_space(1))) unsigned int*)g,
      (__attribute__((address_space(3))) unsigned int*)l, 16, 0, 0);
}

#define SBAR __builtin_amdgcn_sched_barrier(0)
#define BARRIER __builtin_amdgcn_s_barrier()
#define LGKM0 asm volatile("s_waitcnt lgkmcnt(0)" ::: "memory")
#define VMC0 asm volatile("s_waitcnt vmcnt(0)" ::: "memory")

// ---------------------------------------------------------------------------
// fused pre-split: gather-split of embed[seq] + w1 split + w2 split
// blocks [0,8192): gather rows; [8192,8448): w1; [8448,8704): w2
// ---------------------------------------------------------------------------
__global__ __launch_bounds__(256)
void presplit(const int* __restrict__ seq, const float* __restrict__ embed,
              ushort_t* __restrict__ Ah, ushort_t* __restrict__ Al,
              const float* __restrict__ w1, ushort_t* __restrict__ w1h,
              ushort_t* __restrict__ w1l,
              const float* __restrict__ w2, ushort_t* __restrict__ w2h,
              ushort_t* __restrict__ w2l)
{
  const int b = blockIdx.x, tid = threadIdx.x;
  if (b < 8192) {
    const int wid = tid >> 6, lane = tid & 63;
    const int row = b * 4 + wid;
    const float* src = embed + (size_t)seq[row] * 512 + lane * 8;
    const float4 a = *(const float4*)src;
    const float4 c = *(const float4*)(src + 4);
    u16x8 h, l;
    split8(a, c, h, l);
    *(u16x8*)(Ah + (size_t)row * 512 + lane * 8) = h;
    *(u16x8*)(Al + (size_t)row * 512 + lane * 8) = l;
  } else {
    const float* W;  ushort_t *Wh, *Wl;  int i;
    if (b < 8448) { W = w1; Wh = w1h; Wl = w1l; i = (b - 8192) * 256 + tid; }
    else          { W = w2; Wh = w2h; Wl = w2l; i = (b - 8448) * 256 + tid; }
    const float4 a = *(const float4*)(W + (size_t)i * 8);
    const float4 c = *(const float4*)(W + (size_t)i * 8 + 4);
    u16x8 h, l;
    split8(a, c, h, l);
    *(u16x8*)(Wh + (size_t)i * 8) = h;
    *(u16x8*)(Wl + (size_t)i * 8) = l;
  }
}

// ---------------------------------------------------------------------------
// Split-bf16 MFMA GEMM as virtual K'=3K bf16 GEMM, THIRDS-INTERLEAVED:
// virtual tile t -> third t%3, k-tile t/3; thirds: 0=(Ah,Bh) 1=(Al,Bh)
// 2=(Ah,Bl). Consecutive tiles share Ah_k / Bh_k -> re-reads are 1-2 steps
// apart = L2/L1-hot (R8's thirds-major order evicted them, FETCH 156MB).
// 128x128 tile, 4 waves (2Mx2N), per-wave 64x64 = acc[4][4]. BK=64 virtual.
// LDS 64 KB = 2 dbuf x (A 16KB + B 16KB) -> 2 blocks/CU (R8 core, 119us).
// A-panel-grouping swizzle: blocks sharing an A panel (same m-tile) land on
// the SAME XCD at adjacent slots -> A fetched once per XCD, not numN times.
// Rows are 128 B (8 chunks x 16 B) with chunk-XOR (row&7) via pre-swizzled
// global source (0 conflicts measured R4-R10).
// EPI 0: +bias, relu -> Oh/Ol bf16 hi/lo (per-wave LDS bounce, coalesced 8B).
// EPI 1: +bias + embed[seq[row]] -> f32.
// ---------------------------------------------------------------------------
template<int EPI>
__global__ __launch_bounds__(256, 2)
void gemmk(const ushort_t* __restrict__ Ah, const ushort_t* __restrict__ Al,
           const ushort_t* __restrict__ Bh, const ushort_t* __restrict__ Bl,
           const float* __restrict__ bias,
           const int* __restrict__ seq, const float* __restrict__ embed,
           ushort_t* __restrict__ Oh, ushort_t* __restrict__ Ol,
           float* __restrict__ Of, int N, int K)
{
  __shared__ __align__(16) ushort_t lds[32768];   // 64 KB
  const int tid = threadIdx.x;
  const int numN = N >> 7;
  // A-panel-grouping swizzle: slot s -> XCD s%8 (standard idiom); blocks with
  // the same m-tile get the same s%8 and adjacent s -> same XCD, concurrent.
  const int xg = blockIdx.x & 7, jg = blockIdx.x >> 3;
  const int mt = xg + 8 * (jg / numN);
  const int nt = jg - (jg / numN) * numN;
  const int m0 = mt << 7;
  const int n0 = nt << 7;
  const int wid = tid >> 6, lane = tid & 63;
  const int wm = wid >> 1, wn = wid & 1;
  const int l16 = lane & 15, lkb = lane >> 4;

  const int tpt = K >> 6;       // real-K tiles (BK=64)
  const int NT  = 3 * tpt;      // virtual tiles
  const int NI  = NT >> 1;      // iterations (2 tiles each)

  // staging precompute: thread covers chunks tid + j*256 (j=0..3) of each
  // [128 rows][8 chunks x 16B] tile; LDS linear, source chunk-XOR'd by row&7.
  int offA[4], offB[4];         // element offsets (row*K + swizzled col)
#pragma unroll
  for (int j = 0; j < 4; ++j) {
    const int cj = tid + j * 256;
    const int row = cj >> 3;
    const int sc = ((cj & 7) ^ (row & 7)) << 3;
    offA[j] = (m0 + row) * K + sc;
    offB[j] = (n0 + row) * K + sc;
  }

  // thirds-interleaved: third = ts%3, k-offset = (ts/3)*64
  auto stageA = [&](int ts, int buf) {
    const int th = ts % 3;
    const ushort_t* p = ((th == 1) ? Al : Ah) + ((ts / 3) << 6);
    ushort_t* base = lds + buf * 16384 + wid * 512;
#pragma unroll
    for (int j = 0; j < 4; ++j) gl16(p + offA[j], base + j * 2048);
  };
  auto stageB = [&](int ts, int buf) {
    const int th = ts % 3;
    const ushort_t* p = ((th == 2) ? Bl : Bh) + ((ts / 3) << 6);
    ushort_t* base = lds + buf * 16384 + 8192 + wid * 512;
#pragma unroll
    for (int j = 0; j < 4; ++j) gl16(p + offB[j], base + j * 2048);
  };

  bf16x8 fa[4], fb[4];
  f32x4 acc[4][4];
#pragma unroll
  for (int m = 0; m < 4; ++m)
#pragma unroll
    for (int n = 0; n < 4; ++n) acc[m][n] = (f32x4){0.f, 0.f, 0.f, 0.f};

  const int swz = l16 & 7;
  auto ldfrag = [&](int buf, int ks) {
    const int kc = ks * 4;
    const ushort_t* b0 = lds + buf * 16384;
#pragma unroll
    for (int m = 0; m < 4; ++m)
      fa[m] = *(const bf16x8*)(b0 + (wm * 64 + m * 16 + l16) * 64
                                  + (((kc + lkb) ^ swz) << 3));
#pragma unroll
    for (int nf = 0; nf < 4; ++nf)
      fb[nf] = *(const bf16x8*)(b0 + 8192 + (wn * 64 + nf * 16 + l16) * 64
                                  + (((kc + lkb) ^ swz) << 3));
  };
  auto mfma16 = [&]() {
    __builtin_amdgcn_s_setprio(1);
#pragma unroll
    for (int m = 0; m < 4; ++m)
#pragma unroll
      for (int nf = 0; nf < 4; ++nf)
        acc[m][nf] = __builtin_amdgcn_mfma_f32_16x16x32_bf16(
            fa[m], fb[nf], acc[m][nf], 0, 0, 0);
    __builtin_amdgcn_s_setprio(0);
  };

  // prologue: tile 0 staged + verified
  stageA(0, 0); stageB(0, 0);
  VMC0; BARRIER; SBAR;

  for (int i = 0; i < NI; ++i) {
    const int b = 2 * i + 1;
    const bool more = (i + 1 < NI);
    // ph0: tile 2i, ks0
    ldfrag(0, 0); stageA(b, 1); LGKM0; SBAR; mfma16();
    // ph1: tile 2i, ks1; verify tile 2i+1 before its reads
    ldfrag(0, 1); stageB(b, 1); LGKM0; SBAR; mfma16();
    VMC0; BARRIER; SBAR;
    // ph2: tile 2i+1, ks0
    ldfrag(1, 0); if (more) stageA(b + 1, 0); LGKM0; SBAR; mfma16();
    // ph3: tile 2i+1, ks1; verify tile 2i+2
    ldfrag(1, 1); if (more) stageB(b + 1, 0); LGKM0; SBAR; mfma16();
    VMC0; BARRIER; SBAR;
  }

  // epilogue: wave tile 64x64 at rows m0+wm*64, cols n0+wn*64.
  // C/D frag: col=l16 (n), row=lkb*4+ii (m)
  if (EPI == 0) {
    unsigned* pw = (unsigned*)lds + wid * 4096;
    float bv[4];
#pragma unroll
    for (int nf = 0; nf < 4; ++nf) bv[nf] = bias[n0 + wn * 64 + nf * 16 + l16];
#pragma unroll
    for (int m = 0; m < 4; ++m)
#pragma unroll
      for (int nf = 0; nf < 4; ++nf)
#pragma unroll
        for (int ii = 0; ii < 4; ++ii) {
          float v = fmaxf(acc[m][nf][ii] + bv[nf], 0.f);
          const ushort_t h = f2bf(v);
          const ushort_t l = f2bf(v - bf2f(h));
          const int row = m * 16 + lkb * 4 + ii;
          pw[row * 64 + nf * 16 + l16] = ((unsigned)h << 16) | l;
        }
#pragma unroll
    for (int p = 0; p < 16; ++p) {
      const int idx = p * 256 + lane * 4;
      const int row = idx >> 6, col = idx & 63;
      const uint4 w = *(const uint4*)(pw + idx);
      ushort4 hs, ls;
      hs.x = (ushort_t)(w.x >> 16); ls.x = (ushort_t)(w.x & 0xffffu);
      hs.y = (ushort_t)(w.y >> 16); ls.y = (ushort_t)(w.y & 0xffffu);
      hs.z = (ushort_t)(w.z >> 16); ls.z = (ushort_t)(w.z & 0xffffu);
      hs.w = (ushort_t)(w.w >> 16); ls.w = (ushort_t)(w.w & 0xffffu);
      const size_t go = (size_t)(m0 + wm * 64 + row) * N + (n0 + wn * 64 + col);
      *(ushort4*)(Oh + go) = hs;
      *(ushort4*)(Ol + go) = ls;
    }
  } else {
#pragma unroll
    for (int nf = 0; nf < 4; ++nf) {
      const int col = n0 + wn * 64 + nf * 16 + l16;
      const float bvv = bias[col];
#pragma unroll
      for (int m = 0; m < 4; ++m) {
        const int rbase = m0 + wm * 64 + m * 16 + lkb * 4;
#pragma unroll
        for (int ii = 0; ii < 4; ++ii) {
          const int row = rbase + ii;
          float v = acc[m][nf][ii] + bvv;
          v += embed[(size_t)seq[row] * 512 + col];
          Of[(size_t)row * N + col] = v;
        }
      }
    }
  }
}

// in-place LayerNorm + fused gate score + L2 norm; one wave per 512-elem row
__global__ __launch_bounds__(256)
void lnscore_k(float* __restrict__ x, const float* __restrict__ g,
               const float* __restrict__ bt, const float* __restrict__ wg_w,
               const float* __restrict__ wg_b, float* __restrict__ scores,
               float* __restrict__ norms)
{
  const int wid = threadIdx.x >> 6, lane = threadIdx.x & 63;
  const int row = blockIdx.x * 4 + wid;
  float* xr = x + (size_t)row * 512;
  const float4 v0 = *(const float4*)(xr + lane*4);
  const float4 v1 = *(const float4*)(xr + 256 + lane*4);
  float s = v0.x+v0.y+v0.z+v0.w + v1.x+v1.y+v1.z+v1.w;
  s = wsum64(s);
  const float mu = s * (1.f/512.f);
  float ss = (v0.x-mu)*(v0.x-mu) + (v0.y-mu)*(v0.y-mu)
           + (v0.z-mu)*(v0.z-mu) + (v0.w-mu)*(v0.w-mu)
           + (v1.x-mu)*(v1.x-mu) + (v1.y-mu)*(v1.y-mu)
           + (v1.z-mu)*(v1.z-mu) + (v1.w-mu)*(v1.w-mu);
  ss = wsum64(ss);
  const float inv = 1.f / sqrtf(ss * (1.f/512.f) + 1e-5f);
  const float4 g0 = *(const float4*)(g + lane*4);
  const float4 g1 = *(const float4*)(g + 256 + lane*4);
  const float4 c0 = *(const float4*)(bt + lane*4);
  const float4 c1 = *(const float4*)(bt + 256 + lane*4);
  float4 o0, o1;
  o0.x = (v0.x-mu)*inv*g0.x + c0.x;  o0.y = (v0.y-mu)*inv*g0.y + c0.y;
  o0.z = (v0.z-mu)*inv*g0.z + c0.z;  o0.w = (v0.w-mu)*inv*g0.w + c0.w;
  o1.x = (v1.x-mu)*inv*g1.x + c1.x;  o1.y = (v1.y-mu)*inv*g1.y + c1.y;
  o1.z = (v1.z-mu)*inv*g1.z + c1.z;  o1.w = (v1.w-mu)*inv*g1.w + c1.w;
  *(float4*)(xr + lane*4) = o0;
  *(float4*)(xr + 256 + lane*4) = o1;

  const float4 q0 = *(const float4*)(wg_w + lane*4);
  const float4 q1 = *(const float4*)(wg_w + 256 + lane*4);
  float d = o0.x*q0.x + o0.y*q0.y + o0.z*q0.z + o0.w*q0.w
          + o1.x*q1.x + o1.y*q1.y + o1.z*q1.z + o1.w*q1.w;
  float n2 = o0.x*o0.x + o0.y*o0.y + o0.z*o0.z + o0.w*o0.w
           + o1.x*o1.x + o1.y*o1.y + o1.z*o1.z + o1.w*o1.w;
  d = wsum64(d); n2 = wsum64(n2);
  const int b = row >> 10, t = row & 1023;
  if (lane == 0 && t < 1021) {
    scores[b * 1021 + t] = d + wg_b[0];
    norms[b * 1021 + t] = sqrtf(n2);
  }
}

// ---------------------------------------------------------------------------
// Greedy score-ranked selection with cosine dedup; one block per batch row.
// ---------------------------------------------------------------------------
__global__ __launch_bounds__(256, 1)
void select_k(const float* __restrict__ hidden, const float* __restrict__ scores,
              const float* __restrict__ norms, int* __restrict__ selidx_g,
              int* __restrict__ selcnt_g)
{
  __shared__ __align__(16) ushort_t allH[128 * 520];     // 133120 B (keys alias)
  __shared__ ushort_t simS[64 * 128];
  __shared__ ushort_t sortedIdx[1024];
  __shared__ ushort_t selT[64];
  __shared__ ushort_t newPos[64];
  __shared__ int s_count, s_nacc;

  const int b = blockIdx.x, tid = threadIdx.x;
  const int wid = tid >> 6, lane = tid & 63;
  const int l16 = lane & 15, lkb = lane >> 4;

  unsigned long long* keys = (unsigned long long*)allH;
  for (int i = tid; i < 1024; i += 256) {
    const float s = (i < 1021) ? scores[b * 1021 + i] : -INFINITY;
    const unsigned u = __float_as_uint(s);
    const unsigned ms = (u & 0x80000000u) ? ~u : (u | 0x80000000u);
    keys[i] = ((unsigned long long)(~ms) << 32) | (unsigned)i;
  }
  __syncthreads();
  for (int k = 2; k <= 1024; k <<= 1) {
    for (int j = k >> 1; j > 0; j >>= 1) {
      for (int i = tid; i < 1024; i += 256) {
        const int ixj = i ^ j;
        if (ixj > i) {
          const unsigned long long a = keys[i], c = keys[ixj];
          const bool up = ((i & k) == 0);
          if ((a > c) == up) { keys[i] = c; keys[ixj] = a; }
        }
      }
      __syncthreads();
    }
  }
  for (int i = tid; i < 1024; i += 256)
    sortedIdx[i] = (ushort_t)(keys[i] & 0xffffu);
  if (tid == 0) s_count = 0;
  __syncthreads();

  int p = 0;
  while (true) {
    const int count = s_count;
    if (count >= 64 || p >= 1021) break;
    const int C = min(64, 1021 - p);

    {
      const int r = tid >> 2;
      const int seg = (tid & 3) * 128;
      if (r < C) {
        const int t = sortedIdx[p + r];
        const float rn = 1.f / fmaxf(norms[b * 1021 + t], 1e-12f);
        const float* src = hidden + ((size_t)b * 1024 + t) * 512 + seg;
        ushort_t* dst = allH + (64 + r) * 520 + seg;
#pragma unroll
        for (int u0 = 0; u0 < 128; u0 += 8) {
          const float4 x = *(const float4*)(src + u0);
          const float4 y = *(const float4*)(src + u0 + 4);
          u16x8 o;
          o[0] = f2bf(x.x * rn); o[1] = f2bf(x.y * rn);
          o[2] = f2bf(x.z * rn); o[3] = f2bf(x.w * rn);
          o[4] = f2bf(y.x * rn); o[5] = f2bf(y.y * rn);
          o[6] = f2bf(y.z * rn); o[7] = f2bf(y.w * rn);
          *(u16x8*)(dst + u0) = o;
        }
      }
    }
    __syncthreads();

    {
      f32x4 acc[8];
#pragma unroll
      for (int t = 0; t < 8; ++t) acc[t] = (f32x4){0.f, 0.f, 0.f, 0.f};
      const ushort_t* Abase = allH + (64 + (wid << 4) + l16) * 520;
#pragma unroll
      for (int ks = 0; ks < 16; ++ks) {
        const bf16x8 a = *(const bf16x8*)(Abase + ks * 32 + lkb * 8);
#pragma unroll
        for (int t = 0; t < 8; ++t) {
          const bf16x8 bb = *(const bf16x8*)(allH + ((t << 4) + l16) * 520 + ks * 32 + lkb * 8);
          acc[t] = __builtin_amdgcn_mfma_f32_16x16x32_bf16(a, bb, acc[t], 0, 0, 0);
        }
      }
#pragma unroll
      for (int t = 0; t < 8; ++t)
#pragma unroll
        for (int ii = 0; ii < 4; ++ii) {
          const int ri = (wid << 4) + lkb * 4 + ii;
          simS[ri * 128 + (t << 4) + l16] = f2bf(acc[t][ii]);
        }
    }
    __syncthreads();

    if (wid == 0) {
      unsigned long long accMask = 0ull;
      int nacc = 0;
      for (int i = 0; i < C; ++i) {
        float v = -INFINITY;
        if (lane < count) v = bf2f(simS[i * 128 + lane]);
        if ((accMask >> lane) & 1ull) v = fmaxf(v, bf2f(simS[i * 128 + 64 + lane]));
#pragma unroll
        for (int off = 32; off > 0; off >>= 1) v = fmaxf(v, __shfl_xor(v, off, 64));
        const int total = count + nacc;
        const bool ok = (total == 0) || (v <= 0.8f);
        if (total < 64 && ok) {
          if (lane == 0) { selT[total] = sortedIdx[p + i]; newPos[nacc] = (ushort_t)i; }
          accMask |= (1ull << i);
          ++nacc;
          if (total + 1 == 64) break;
        }
      }
      if (lane == 0) { s_nacc = nacc; s_count = count + nacc; }
    }
    __syncthreads();

    {
      const int nacc = s_nacc;
      for (int a = wid; a < nacc; a += 4) {
        const int srcrow = 64 + (int)newPos[a];
        const int dstrow = count + a;
        const u16x8 val = *(const u16x8*)(allH + srcrow * 520 + lane * 8);
        *(u16x8*)(allH + dstrow * 520 + lane * 8) = val;
      }
    }
    p += C;
    __syncthreads();
  }

  __syncthreads();
  if (tid < 64) selidx_g[b * 64 + tid] = (tid < s_count) ? (int)selT[tid] : 0;
  if (tid == 0) selcnt_g[b] = s_count;
}

// q = hidden[:, T-2, :] @ q_w^T + q_b ; one wave per output element
__global__ __launch_bounds__(256)
void q_k(const float* __restrict__ hidden, const float* __restrict__ q_w,
         const float* __restrict__ q_b, float* __restrict__ qv)
{
  const int wid = threadIdx.x >> 6, lane = threadIdx.x & 63;
  const int o = blockIdx.x * 4 + wid;
  const int b = o >> 9, n = o & 511;
  const float* hr = hidden + ((size_t)b*1024 + 1022) * 512;
  const float* wr = q_w + (size_t)n * 512;
  const float4 h0 = *(const float4*)(hr + lane*4);
  const float4 h1 = *(const float4*)(hr + 256 + lane*4);
  const float4 w0 = *(const float4*)(wr + lane*4);
  const float4 w1 = *(const float4*)(wr + 256 + lane*4);
  float d = h0.x*w0.x + h0.y*w0.y + h0.z*w0.z + h0.w*w0.w
          + h1.x*w1.x + h1.y*w1.y + h1.z*w1.z + h1.w*w1.w;
  d = wsum64(d);
  if (lane == 0) qv[o] = d + q_b[n];
}

// masked softmax attention over selected memory; one block per batch
__global__ __launch_bounds__(256)
void attn_k(const float* __restrict__ hidden, const float* __restrict__ qv,
            const int* __restrict__ selidx_g, const int* __restrict__ selcnt_g,
            float* __restrict__ ctx)
{
  const int b = blockIdx.x, tid = threadIdx.x;
  const int wid = tid >> 6, lane = tid & 63;
  __shared__ float qs[512];
  __shared__ int sidx[64];
  __shared__ float sv[64];
  __shared__ float av[64];
  const int count = selcnt_g[b];
  for (int i = tid; i < 512; i += 256) qs[i] = qv[b*512 + i];
  if (tid < 64) sidx[tid] = selidx_g[b*64 + tid];
  __syncthreads();
  for (int m = wid; m < 64; m += 4) {
    float sval = -1e9f;
    if (m < count) {
      const float* hr = hidden + ((size_t)b*1024 + sidx[m]) * 512;
      const float4 a0 = *(const float4*)(hr + lane*4);
      const float4 a1 = *(const float4*)(hr + 256 + lane*4);
      const float4 q0 = *(const float4*)(&qs[lane*4]);
      const float4 q1 = *(const float4*)(&qs[256 + lane*4]);
      float d = a0.x*q0.x + a0.y*q0.y + a0.z*q0.z + a0.w*q0.w
              + a1.x*q1.x + a1.y*q1.y + a1.z*q1.z + a1.w*q1.w;
      d = wsum64(d);
      sval = d;
    }
    if (lane == 0) sv[m] = sval;
  }
  __syncthreads();
  if (tid < 64) {
    const float v = sv[tid];
    float mx = v;
#pragma unroll
    for (int off = 32; off > 0; off >>= 1) mx = fmaxf(mx, __shfl_xor(mx, off, 64));
    const float e = expf(v - mx);
    float ssum = e;
#pragma unroll
    for (int off = 32; off > 0; off >>= 1) ssum += __shfl_xor(ssum, off, 64);
    av[tid] = e / ssum;
  }
  __syncthreads();
  for (int n = tid; n < 512; n += 256) {
    float a = 0.f;
    for (int m = 0; m < count; ++m)
      a += av[m] * hidden[((size_t)b*1024 + sidx[m]) * 512 + n];
    ctx[b*512 + n] = a;
  }
}

// ---------------------------------------------------------------------------
// out = ctx @ out_w^T + out_b via streaming split-bf16 MFMA (R7, kept).
// ---------------------------------------------------------------------------
__global__ __launch_bounds__(256, 2)
void out_k(const float* __restrict__ ctx, const float* __restrict__ out_w,
           const float* __restrict__ out_b, float* __restrict__ out)
{
  __shared__ __align__(16) ushort_t ctxH[32 * 520];
  __shared__ __align__(16) ushort_t ctxL[32 * 520];
  const int tid = threadIdx.x;
  const int wid = tid >> 6, lane = tid & 63;
  const int l16 = lane & 15, lkb = lane >> 4;

  {
    const int row = tid >> 3;
    const int c0 = (tid & 7) * 64;
    const float* src = ctx + row * 512 + c0;
    ushort_t* dh = ctxH + row * 520 + c0;
    ushort_t* dl = ctxL + row * 520 + c0;
#pragma unroll
    for (int u0 = 0; u0 < 64; u0 += 8) {
      const float4 a = *(const float4*)(src + u0);
      const float4 b = *(const float4*)(src + u0 + 4);
      u16x8 h, l;
      split8(a, b, h, l);
      *(u16x8*)(dh + u0) = h;
      *(u16x8*)(dl + u0) = l;
    }
  }
  __syncthreads();

  const int v = blockIdx.x * 64 + wid * 16 + l16;
  const float* wr = out_w + (size_t)v * 512 + lkb * 8;
  f32x4 acc0 = (f32x4){0.f, 0.f, 0.f, 0.f};
  f32x4 acc1 = (f32x4){0.f, 0.f, 0.f, 0.f};
#pragma unroll
  for (int ks = 0; ks < 16; ++ks) {
    const float4 wa = *(const float4*)(wr + ks * 32);
    const float4 wb = *(const float4*)(wr + ks * 32 + 4);
    u16x8 wh, wl;
    split8(wa, wb, wh, wl);
    const bf16x8 whb = (bf16x8)wh, wlb = (bf16x8)wl;
    const int co = ks * 32 + lkb * 8;
    const bf16x8 ch0 = *(const bf16x8*)(ctxH + l16 * 520 + co);
    const bf16x8 cl0 = *(const bf16x8*)(ctxL + l16 * 520 + co);
    const bf16x8 ch1 = *(const bf16x8*)(ctxH + (16 + l16) * 520 + co);
    const bf16x8 cl1 = *(const bf16x8*)(ctxL + (16 + l16) * 520 + co);
    acc0 = __builtin_amdgcn_mfma_f32_16x16x32_bf16(ch0, whb, acc0, 0, 0, 0);
    acc0 = __builtin_amdgcn_mfma_f32_16x16x32_bf16(cl0, whb, acc0, 0, 0, 0);
    acc0 = __builtin_amdgcn_mfma_f32_16x16x32_bf16(ch0, wlb, acc0, 0, 0, 0);
    acc1 = __builtin_amdgcn_mfma_f32_16x16x32_bf16(ch1, whb, acc1, 0, 0, 0);
    acc1 = __builtin_amdgcn_mfma_f32_16x16x32_bf16(cl1, whb, acc1, 0, 0, 0);
    acc1 = __builtin_amdgcn_mfma_f32_16x16x32_bf16(ch1, wlb, acc1, 0, 0, 0);
  }
  const float bv = out_b[v];
#pragma unroll
  for (int i = 0; i < 4; ++i) {
    out[(size_t)(lkb * 4 + i) * 32000 + v] = acc0[i] + bv;
    out[(size_t)(16 + lkb * 4 + i) * 32000 + v] = acc1[i] + bv;
  }
}

extern "C" void kernel_launch(void* const* d_in, const int* in_sizes, int n_in,
                              void* d_out, int out_size, void* d_ws, size_t ws_size,
                              hipStream_t stream)
{
  const int*   seq   = (const int*)d_in[0];
  const float* embed = (const float*)d_in[1];
  const float* w1    = (const float*)d_in[2];
  const float* b1    = (const float*)d_in[3];
  const float* w2    = (const float*)d_in[4];
  const float* b2    = (const float*)d_in[5];
  const float* ln_g  = (const float*)d_in[6];
  const float* ln_b  = (const float*)d_in[7];
  const float* wg_w  = (const float*)d_in[8];
  const float* wg_b  = (const float*)d_in[9];
  const float* q_w   = (const float*)d_in[10];
  const float* q_b   = (const float*)d_in[11];
  const float* out_w = (const float*)d_in[12];
  const float* out_b = (const float*)d_in[13];
  float* out = (float*)d_out;

  char* ws = (char*)d_ws;
  size_t off = 0;
  auto alloc = [&](size_t bytes) {
    void* p = ws + off;
    off += (bytes + 255) & ~(size_t)255;
    return p;
  };
  void* xA = alloc((size_t)32768 * 512 * 4);            // 67 MB
  ushort_t* Ahid = (ushort_t*)xA;
  ushort_t* Alid = Ahid + (size_t)32768 * 512;
  float* xbuf = (float*)xA;
  ushort_t* ff1h = (ushort_t*)alloc((size_t)32768 * 1024 * 2);  // 67 MB
  ushort_t* ff1l = (ushort_t*)alloc((size_t)32768 * 1024 * 2);  // 67 MB
  ushort_t* w1h = (ushort_t*)alloc((size_t)1024 * 512 * 2);
  ushort_t* w1l = (ushort_t*)alloc((size_t)1024 * 512 * 2);
  ushort_t* w2h = (ushort_t*)alloc((size_t)512 * 1024 * 2);
  ushort_t* w2l = (ushort_t*)alloc((size_t)512 * 1024 * 2);
  float* scores = (float*)alloc((size_t)32 * 1021 * 4);
  float* norms  = (float*)alloc((size_t)32 * 1021 * 4);
  int*   selidx = (int*)alloc((size_t)32 * 64 * 4);
  int*   selcnt = (int*)alloc((size_t)32 * 4);
  float* qbuf   = (float*)alloc((size_t)32 * 512 * 4);
  float* ctxb   = (float*)alloc((size_t)32 * 512 * 4);

  // fused pre-split (gather + w1 + w2)
  presplit<<<8704, 256, 0, stream>>>(seq, embed, Ahid, Alid,
                                     w1, w1h, w1l, w2, w2h, w2l);

  // FF1: relu(h @ w1^T + b1) -> ff1 hi/lo bf16  [32768,1024]
  gemmk<0><<<2048, 256, 0, stream>>>(Ahid, Alid, w1h, w1l, b1,
                                     nullptr, nullptr, ff1h, ff1l, nullptr,
                                     1024, 512);
  // FF2: ff1 @ w2^T + b2 + embed[seq] -> xbuf f32 [32768,512]
  gemmk<1><<<1024, 256, 0, stream>>>(ff1h, ff1l, w2h, w2l, b2,
                                     seq, embed, nullptr, nullptr, xbuf,
                                     512, 1024);
  lnscore_k<<<8192, 256, 0, stream>>>(xbuf, ln_g, ln_b, wg_w, wg_b, scores, norms);
  select_k<<<32, 256, 0, stream>>>(xbuf, scores, norms, selidx, selcnt);
  q_k<<<4096, 256, 0, stream>>>(xbuf, q_w, q_b, qbuf);
  attn_k<<<32, 256, 0, stream>>>(xbuf, qbuf, selidx, selcnt, ctxb);
  out_k<<<500, 256, 0, stream>>>(ctxb, out_w, out_b, out);
}

// Round 12
// 318.240 us; speedup vs baseline: 1.3213x; 1.1753x over previous
//
#include <hip/hip_runtime.h>
#include <math.h>

typedef unsigned short ushort_t;
typedef short bf16x8 __attribute__((ext_vector_type(8)));
typedef unsigned short u16x8 __attribute__((ext_vector_type(8)));
typedef float f32x4 __attribute__((ext_vector_type(4)));

__device__ __forceinline__ float wsum64(float v) {
#pragma unroll
  for (int off = 32; off > 0; off >>= 1) v += __shfl_xor(v, off, 64);
  return v;
}

__device__ __forceinline__ ushort_t f2bf(float x) {   // RNE f32->bf16
  unsigned u = __float_as_uint(x);
  return (ushort_t)((u + 0x7fffu + ((u >> 16) & 1u)) >> 16);
}
__device__ __forceinline__ float bf2f(ushort_t h) {
  return __uint_as_float(((unsigned)h) << 16);
}

__device__ __forceinline__ void split8(const float4 a, const float4 b,
                                       u16x8& h, u16x8& l) {
  h[0]=f2bf(a.x); l[0]=f2bf(a.x-bf2f(h[0]));
  h[1]=f2bf(a.y); l[1]=f2bf(a.y-bf2f(h[1]));
  h[2]=f2bf(a.z); l[2]=f2bf(a.z-bf2f(h[2]));
  h[3]=f2bf(a.w); l[3]=f2bf(a.w-bf2f(h[3]));
  h[4]=f2bf(b.x); l[4]=f2bf(b.x-bf2f(h[4]));
  h[5]=f2bf(b.y); l[5]=f2bf(b.y-bf2f(h[5]));
  h[6]=f2bf(b.z); l[6]=f2bf(b.z-bf2f(h[6]));
  h[7]=f2bf(b.w); l[7]=f2bf(b.w-bf2f(h[7]));
}

// async global(per-lane) -> LDS(wave-uniform base + lane*16B), 16B per lane
__device__ __forceinline__ void gl16(const void* g, const void* l) {
  __builtin_amdgcn_global_load_lds(
      (const __attribute__((address_space(1))) unsigned int*)g,
      (__attribute__((address_space(3))) unsigned int*)l, 16, 0, 0);
}

#define SBAR __builtin_amdgcn_sched_barrier(0)
#define BARRIER __builtin_amdgcn_s_barrier()
#define LGKM0 asm volatile("s_waitcnt lgkmcnt(0)" ::: "memory")
#define VMC0 asm volatile("s_waitcnt vmcnt(0)" ::: "memory")

// ---------------------------------------------------------------------------
// fused pre-split: gather-split of embed[seq] + w1 hi + w2 hi
// blocks [0,8192): gather rows; [8192,8448): w1; [8448,8704): w2
// (weight lo planes are dead under the 2-term GEMM scheme -> not stored)
// ---------------------------------------------------------------------------
__global__ __launch_bounds__(256)
void presplit(const int* __restrict__ seq, const float* __restrict__ embed,
              ushort_t* __restrict__ Ah, ushort_t* __restrict__ Al,
              const float* __restrict__ w1, ushort_t* __restrict__ w1h,
              const float* __restrict__ w2, ushort_t* __restrict__ w2h)
{
  const int b = blockIdx.x, tid = threadIdx.x;
  if (b < 8192) {
    const int wid = tid >> 6, lane = tid & 63;
    const int row = b * 4 + wid;
    const float* src = embed + (size_t)seq[row] * 512 + lane * 8;
    const float4 a = *(const float4*)src;
    const float4 c = *(const float4*)(src + 4);
    u16x8 h, l;
    split8(a, c, h, l);
    *(u16x8*)(Ah + (size_t)row * 512 + lane * 8) = h;
    *(u16x8*)(Al + (size_t)row * 512 + lane * 8) = l;
  } else {
    const float* W;  ushort_t* Wh;  int i;
    if (b < 8448) { W = w1; Wh = w1h; i = (b - 8192) * 256 + tid; }
    else          { W = w2; Wh = w2h; i = (b - 8448) * 256 + tid; }
    const float4 a = *(const float4*)(W + (size_t)i * 8);
    const float4 c = *(const float4*)(W + (size_t)i * 8 + 4);
    u16x8 h, l;
    split8(a, c, h, l);
    *(u16x8*)(Wh + (size_t)i * 8) = h;
  }
}

// ---------------------------------------------------------------------------
// 2-TERM split-bf16 MFMA GEMM:  C ~= (Ah+Al).Bh^T  as virtual K'=2K bf16 GEMM
// interleaved: virtual tile ts -> A-third ts&1 (0=Ah,1=Al), k-tile ts>>1;
// B is always Bh_k (re-staged, L1/L2-hot since consecutive tiles share it).
// Error: omitted A.Bl term ~2^-10.5 rel -> score err sigma ~1e-4 << rank-64
// score gap ~3.7e-3 (selection-safe; see R12 analysis).
// 128x128 tile, 4 waves (2Mx2N), per-wave 64x64 = acc[4][4]. BK=64 virtual.
// LDS 64 KB = 2 dbuf x (A 16KB + B 16KB) -> 2 blocks/CU (R8/R11 core).
// A-panel-grouping swizzle: blocks sharing an A panel on the same XCD.
// Rows 128 B (8 chunks x 16 B), chunk-XOR (row&7) via pre-swizzled source.
// EPI 0: +bias, relu -> Oh/Ol bf16 hi/lo (per-wave LDS bounce, coalesced 8B).
// EPI 1: +bias + embed[seq[row]] -> f32.
// ---------------------------------------------------------------------------
template<int EPI>
__global__ __launch_bounds__(256, 2)
void gemmk(const ushort_t* __restrict__ Ah, const ushort_t* __restrict__ Al,
           const ushort_t* __restrict__ Bh,
           const float* __restrict__ bias,
           const int* __restrict__ seq, const float* __restrict__ embed,
           ushort_t* __restrict__ Oh, ushort_t* __restrict__ Ol,
           float* __restrict__ Of, int N, int K)
{
  __shared__ __align__(16) ushort_t lds[32768];   // 64 KB
  const int tid = threadIdx.x;
  const int numN = N >> 7;
  const int xg = blockIdx.x & 7, jg = blockIdx.x >> 3;
  const int mt = xg + 8 * (jg / numN);
  const int nt = jg - (jg / numN) * numN;
  const int m0 = mt << 7;
  const int n0 = nt << 7;
  const int wid = tid >> 6, lane = tid & 63;
  const int wm = wid >> 1, wn = wid & 1;
  const int l16 = lane & 15, lkb = lane >> 4;

  const int tpt = K >> 6;       // real-K tiles (BK=64)
  const int NT  = 2 * tpt;      // virtual tiles (2-term)
  const int NI  = NT >> 1;      // iterations (2 tiles each)

  int offA[4], offB[4];         // element offsets (row*K + swizzled col)
#pragma unroll
  for (int j = 0; j < 4; ++j) {
    const int cj = tid + j * 256;
    const int row = cj >> 3;
    const int sc = ((cj & 7) ^ (row & 7)) << 3;
    offA[j] = (m0 + row) * K + sc;
    offB[j] = (n0 + row) * K + sc;
  }

  // 2-term interleaved: A-third = ts&1, k-offset = (ts>>1)*64
  auto stageA = [&](int ts, int buf) {
    const ushort_t* p = ((ts & 1) ? Al : Ah) + ((ts >> 1) << 6);
    ushort_t* base = lds + buf * 16384 + wid * 512;
#pragma unroll
    for (int j = 0; j < 4; ++j) gl16(p + offA[j], base + j * 2048);
  };
  auto stageB = [&](int ts, int buf) {
    const ushort_t* p = Bh + ((ts >> 1) << 6);
    ushort_t* base = lds + buf * 16384 + 8192 + wid * 512;
#pragma unroll
    for (int j = 0; j < 4; ++j) gl16(p + offB[j], base + j * 2048);
  };

  bf16x8 fa[4], fb[4];
  f32x4 acc[4][4];
#pragma unroll
  for (int m = 0; m < 4; ++m)
#pragma unroll
    for (int n = 0; n < 4; ++n) acc[m][n] = (f32x4){0.f, 0.f, 0.f, 0.f};

  const int swz = l16 & 7;
  auto ldfrag = [&](int buf, int ks) {
    const int kc = ks * 4;
    const ushort_t* b0 = lds + buf * 16384;
#pragma unroll
    for (int m = 0; m < 4; ++m)
      fa[m] = *(const bf16x8*)(b0 + (wm * 64 + m * 16 + l16) * 64
                                  + (((kc + lkb) ^ swz) << 3));
#pragma unroll
    for (int nf = 0; nf < 4; ++nf)
      fb[nf] = *(const bf16x8*)(b0 + 8192 + (wn * 64 + nf * 16 + l16) * 64
                                  + (((kc + lkb) ^ swz) << 3));
  };
  auto mfma16 = [&]() {
    __builtin_amdgcn_s_setprio(1);
#pragma unroll
    for (int m = 0; m < 4; ++m)
#pragma unroll
      for (int nf = 0; nf < 4; ++nf)
        acc[m][nf] = __builtin_amdgcn_mfma_f32_16x16x32_bf16(
            fa[m], fb[nf], acc[m][nf], 0, 0, 0);
    __builtin_amdgcn_s_setprio(0);
  };

  // prologue: tile 0 staged + verified
  stageA(0, 0); stageB(0, 0);
  VMC0; BARRIER; SBAR;

  for (int i = 0; i < NI; ++i) {
    const int b = 2 * i + 1;
    const bool more = (i + 1 < NI);
    // ph0: tile 2i, ks0
    ldfrag(0, 0); stageA(b, 1); LGKM0; SBAR; mfma16();
    // ph1: tile 2i, ks1; verify tile 2i+1 before its reads
    ldfrag(0, 1); stageB(b, 1); LGKM0; SBAR; mfma16();
    VMC0; BARRIER; SBAR;
    // ph2: tile 2i+1, ks0
    ldfrag(1, 0); if (more) stageA(b + 1, 0); LGKM0; SBAR; mfma16();
    // ph3: tile 2i+1, ks1; verify tile 2i+2
    ldfrag(1, 1); if (more) stageB(b + 1, 0); LGKM0; SBAR; mfma16();
    VMC0; BARRIER; SBAR;
  }

  // epilogue: wave tile 64x64 at rows m0+wm*64, cols n0+wn*64.
  // C/D frag: col=l16 (n), row=lkb*4+ii (m)
  if (EPI == 0) {
    unsigned* pw = (unsigned*)lds + wid * 4096;
    float bv[4];
#pragma unroll
    for (int nf = 0; nf < 4; ++nf) bv[nf] = bias[n0 + wn * 64 + nf * 16 + l16];
#pragma unroll
    for (int m = 0; m < 4; ++m)
#pragma unroll
      for (int nf = 0; nf < 4; ++nf)
#pragma unroll
        for (int ii = 0; ii < 4; ++ii) {
          float v = fmaxf(acc[m][nf][ii] + bv[nf], 0.f);
          const ushort_t h = f2bf(v);
          const ushort_t l = f2bf(v - bf2f(h));
          const int row = m * 16 + lkb * 4 + ii;
          pw[row * 64 + nf * 16 + l16] = ((unsigned)h << 16) | l;
        }
#pragma unroll
    for (int p = 0; p < 16; ++p) {
      const int idx = p * 256 + lane * 4;
      const int row = idx >> 6, col = idx & 63;
      const uint4 w = *(const uint4*)(pw + idx);
      ushort4 hs, ls;
      hs.x = (ushort_t)(w.x >> 16); ls.x = (ushort_t)(w.x & 0xffffu);
      hs.y = (ushort_t)(w.y >> 16); ls.y = (ushort_t)(w.y & 0xffffu);
      hs.z = (ushort_t)(w.z >> 16); ls.z = (ushort_t)(w.z & 0xffffu);
      hs.w = (ushort_t)(w.w >> 16); ls.w = (ushort_t)(w.w & 0xffffu);
      const size_t go = (size_t)(m0 + wm * 64 + row) * N + (n0 + wn * 64 + col);
      *(ushort4*)(Oh + go) = hs;
      *(ushort4*)(Ol + go) = ls;
    }
  } else {
#pragma unroll
    for (int nf = 0; nf < 4; ++nf) {
      const int col = n0 + wn * 64 + nf * 16 + l16;
      const float bvv = bias[col];
#pragma unroll
      for (int m = 0; m < 4; ++m) {
        const int rbase = m0 + wm * 64 + m * 16 + lkb * 4;
#pragma unroll
        for (int ii = 0; ii < 4; ++ii) {
          const int row = rbase + ii;
          float v = acc[m][nf][ii] + bvv;
          v += embed[(size_t)seq[row] * 512 + col];
          Of[(size_t)row * N + col] = v;
        }
      }
    }
  }
}

// in-place LayerNorm + fused gate score + L2 norm; one wave per 512-elem row
__global__ __launch_bounds__(256)
void lnscore_k(float* __restrict__ x, const float* __restrict__ g,
               const float* __restrict__ bt, const float* __restrict__ wg_w,
               const float* __restrict__ wg_b, float* __restrict__ scores,
               float* __restrict__ norms)
{
  const int wid = threadIdx.x >> 6, lane = threadIdx.x & 63;
  const int row = blockIdx.x * 4 + wid;
  float* xr = x + (size_t)row * 512;
  const float4 v0 = *(const float4*)(xr + lane*4);
  const float4 v1 = *(const float4*)(xr + 256 + lane*4);
  float s = v0.x+v0.y+v0.z+v0.w + v1.x+v1.y+v1.z+v1.w;
  s = wsum64(s);
  const float mu = s * (1.f/512.f);
  float ss = (v0.x-mu)*(v0.x-mu) + (v0.y-mu)*(v0.y-mu)
           + (v0.z-mu)*(v0.z-mu) + (v0.w-mu)*(v0.w-mu)
           + (v1.x-mu)*(v1.x-mu) + (v1.y-mu)*(v1.y-mu)
           + (v1.z-mu)*(v1.z-mu) + (v1.w-mu)*(v1.w-mu);
  ss = wsum64(ss);
  const float inv = 1.f / sqrtf(ss * (1.f/512.f) + 1e-5f);
  const float4 g0 = *(const float4*)(g + lane*4);
  const float4 g1 = *(const float4*)(g + 256 + lane*4);
  const float4 c0 = *(const float4*)(bt + lane*4);
  const float4 c1 = *(const float4*)(bt + 256 + lane*4);
  float4 o0, o1;
  o0.x = (v0.x-mu)*inv*g0.x + c0.x;  o0.y = (v0.y-mu)*inv*g0.y + c0.y;
  o0.z = (v0.z-mu)*inv*g0.z + c0.z;  o0.w = (v0.w-mu)*inv*g0.w + c0.w;
  o1.x = (v1.x-mu)*inv*g1.x + c1.x;  o1.y = (v1.y-mu)*inv*g1.y + c1.y;
  o1.z = (v1.z-mu)*inv*g1.z + c1.z;  o1.w = (v1.w-mu)*inv*g1.w + c1.w;
  *(float4*)(xr + lane*4) = o0;
  *(float4*)(xr + 256 + lane*4) = o1;

  const float4 q0 = *(const float4*)(wg_w + lane*4);
  const float4 q1 = *(const float4*)(wg_w + 256 + lane*4);
  float d = o0.x*q0.x + o0.y*q0.y + o0.z*q0.z + o0.w*q0.w
          + o1.x*q1.x + o1.y*q1.y + o1.z*q1.z + o1.w*q1.w;
  float n2 = o0.x*o0.x + o0.y*o0.y + o0.z*o0.z + o0.w*o0.w
           + o1.x*o1.x + o1.y*o1.y + o1.z*o1.z + o1.w*o1.w;
  d = wsum64(d); n2 = wsum64(n2);
  const int b = row >> 10, t = row & 1023;
  if (lane == 0 && t < 1021) {
    scores[b * 1021 + t] = d + wg_b[0];
    norms[b * 1021 + t] = sqrtf(n2);
  }
}

// ---------------------------------------------------------------------------
// Greedy score-ranked selection with cosine dedup; one block per batch row.
// ---------------------------------------------------------------------------
__global__ __launch_bounds__(256, 1)
void select_k(const float* __restrict__ hidden, const float* __restrict__ scores,
              const float* __restrict__ norms, int* __restrict__ selidx_g,
              int* __restrict__ selcnt_g)
{
  __shared__ __align__(16) ushort_t allH[128 * 520];     // 133120 B (keys alias)
  __shared__ ushort_t simS[64 * 128];
  __shared__ ushort_t sortedIdx[1024];
  __shared__ ushort_t selT[64];
  __shared__ ushort_t newPos[64];
  __shared__ int s_count, s_nacc;

  const int b = blockIdx.x, tid = threadIdx.x;
  const int wid = tid >> 6, lane = tid & 63;
  const int l16 = lane & 15, lkb = lane >> 4;

  unsigned long long* keys = (unsigned long long*)allH;
  for (int i = tid; i < 1024; i += 256) {
    const float s = (i < 1021) ? scores[b * 1021 + i] : -INFINITY;
    const unsigned u = __float_as_uint(s);
    const unsigned ms = (u & 0x80000000u) ? ~u : (u | 0x80000000u);
    keys[i] = ((unsigned long long)(~ms) << 32) | (unsigned)i;
  }
  __syncthreads();
  for (int k = 2; k <= 1024; k <<= 1) {
    for (int j = k >> 1; j > 0; j >>= 1) {
      for (int i = tid; i < 1024; i += 256) {
        const int ixj = i ^ j;
        if (ixj > i) {
          const unsigned long long a = keys[i], c = keys[ixj];
          const bool up = ((i & k) == 0);
          if ((a > c) == up) { keys[i] = c; keys[ixj] = a; }
        }
      }
      __syncthreads();
    }
  }
  for (int i = tid; i < 1024; i += 256)
    sortedIdx[i] = (ushort_t)(keys[i] & 0xffffu);
  if (tid == 0) s_count = 0;
  __syncthreads();

  int p = 0;
  while (true) {
    const int count = s_count;
    if (count >= 64 || p >= 1021) break;
    const int C = min(64, 1021 - p);

    {
      const int r = tid >> 2;
      const int seg = (tid & 3) * 128;
      if (r < C) {
        const int t = sortedIdx[p + r];
        const float rn = 1.f / fmaxf(norms[b * 1021 + t], 1e-12f);
        const float* src = hidden + ((size_t)b * 1024 + t) * 512 + seg;
        ushort_t* dst = allH + (64 + r) * 520 + seg;
#pragma unroll
        for (int u0 = 0; u0 < 128; u0 += 8) {
          const float4 x = *(const float4*)(src + u0);
          const float4 y = *(const float4*)(src + u0 + 4);
          u16x8 o;
          o[0] = f2bf(x.x * rn); o[1] = f2bf(x.y * rn);
          o[2] = f2bf(x.z * rn); o[3] = f2bf(x.w * rn);
          o[4] = f2bf(y.x * rn); o[5] = f2bf(y.y * rn);
          o[6] = f2bf(y.z * rn); o[7] = f2bf(y.w * rn);
          *(u16x8*)(dst + u0) = o;
        }
      }
    }
    __syncthreads();

    {
      f32x4 acc[8];
#pragma unroll
      for (int t = 0; t < 8; ++t) acc[t] = (f32x4){0.f, 0.f, 0.f, 0.f};
      const ushort_t* Abase = allH + (64 + (wid << 4) + l16) * 520;
#pragma unroll
      for (int ks = 0; ks < 16; ++ks) {
        const bf16x8 a = *(const bf16x8*)(Abase + ks * 32 + lkb * 8);
#pragma unroll
        for (int t = 0; t < 8; ++t) {
          const bf16x8 bb = *(const bf16x8*)(allH + ((t << 4) + l16) * 520 + ks * 32 + lkb * 8);
          acc[t] = __builtin_amdgcn_mfma_f32_16x16x32_bf16(a, bb, acc[t], 0, 0, 0);
        }
      }
#pragma unroll
      for (int t = 0; t < 8; ++t)
#pragma unroll
        for (int ii = 0; ii < 4; ++ii) {
          const int ri = (wid << 4) + lkb * 4 + ii;
          simS[ri * 128 + (t << 4) + l16] = f2bf(acc[t][ii]);
        }
    }
    __syncthreads();

    if (wid == 0) {
      unsigned long long accMask = 0ull;
      int nacc = 0;
      for (int i = 0; i < C; ++i) {
        float v = -INFINITY;
        if (lane < count) v = bf2f(simS[i * 128 + lane]);
        if ((accMask >> lane) & 1ull) v = fmaxf(v, bf2f(simS[i * 128 + 64 + lane]));
#pragma unroll
        for (int off = 32; off > 0; off >>= 1) v = fmaxf(v, __shfl_xor(v, off, 64));
        const int total = count + nacc;
        const bool ok = (total == 0) || (v <= 0.8f);
        if (total < 64 && ok) {
          if (lane == 0) { selT[total] = sortedIdx[p + i]; newPos[nacc] = (ushort_t)i; }
          accMask |= (1ull << i);
          ++nacc;
          if (total + 1 == 64) break;
        }
      }
      if (lane == 0) { s_nacc = nacc; s_count = count + nacc; }
    }
    __syncthreads();

    {
      const int nacc = s_nacc;
      for (int a = wid; a < nacc; a += 4) {
        const int srcrow = 64 + (int)newPos[a];
        const int dstrow = count + a;
        const u16x8 val = *(const u16x8*)(allH + srcrow * 520 + lane * 8);
        *(u16x8*)(allH + dstrow * 520 + lane * 8) = val;
      }
    }
    p += C;
    __syncthreads();
  }

  __syncthreads();
  if (tid < 64) selidx_g[b * 64 + tid] = (tid < s_count) ? (int)selT[tid] : 0;
  if (tid == 0) selcnt_g[b] = s_count;
}

// q = hidden[:, T-2, :] @ q_w^T + q_b ; one wave per output element
__global__ __launch_bounds__(256)
void q_k(const float* __restrict__ hidden, const float* __restrict__ q_w,
         const float* __restrict__ q_b, float* __restrict__ qv)
{
  const int wid = threadIdx.x >> 6, lane = threadIdx.x & 63;
  const int o = blockIdx.x * 4 + wid;
  const int b = o >> 9, n = o & 511;
  const float* hr = hidden + ((size_t)b*1024 + 1022) * 512;
  const float* wr = q_w + (size_t)n * 512;
  const float4 h0 = *(const float4*)(hr + lane*4);
  const float4 h1 = *(const float4*)(hr + 256 + lane*4);
  const float4 w0 = *(const float4*)(wr + lane*4);
  const float4 w1 = *(const float4*)(wr + 256 + lane*4);
  float d = h0.x*w0.x + h0.y*w0.y + h0.z*w0.z + h0.w*w0.w
          + h1.x*w1.x + h1.y*w1.y + h1.z*w1.z + h1.w*w1.w;
  d = wsum64(d);
  if (lane == 0) qv[o] = d + q_b[n];
}

// masked softmax attention over selected memory; one block per batch
__global__ __launch_bounds__(256)
void attn_k(const float* __restrict__ hidden, const float* __restrict__ qv,
            const int* __restrict__ selidx_g, const int* __restrict__ selcnt_g,
            float* __restrict__ ctx)
{
  const int b = blockIdx.x, tid = threadIdx.x;
  const int wid = tid >> 6, lane = tid & 63;
  __shared__ float qs[512];
  __shared__ int sidx[64];
  __shared__ float sv[64];
  __shared__ float av[64];
  const int count = selcnt_g[b];
  for (int i = tid; i < 512; i += 256) qs[i] = qv[b*512 + i];
  if (tid < 64) sidx[tid] = selidx_g[b*64 + tid];
  __syncthreads();
  for (int m = wid; m < 64; m += 4) {
    float sval = -1e9f;
    if (m < count) {
      const float* hr = hidden + ((size_t)b*1024 + sidx[m]) * 512;
      const float4 a0 = *(const float4*)(hr + lane*4);
      const float4 a1 = *(const float4*)(hr + 256 + lane*4);
      const float4 q0 = *(const float4*)(&qs[lane*4]);
      const float4 q1 = *(const float4*)(&qs[256 + lane*4]);
      float d = a0.x*q0.x + a0.y*q0.y + a0.z*q0.z + a0.w*q0.w
              + a1.x*q1.x + a1.y*q1.y + a1.z*q1.z + a1.w*q1.w;
      d = wsum64(d);
      sval = d;
    }
    if (lane == 0) sv[m] = sval;
  }
  __syncthreads();
  if (tid < 64) {
    const float v = sv[tid];
    float mx = v;
#pragma unroll
    for (int off = 32; off > 0; off >>= 1) mx = fmaxf(mx, __shfl_xor(mx, off, 64));
    const float e = expf(v - mx);
    float ssum = e;
#pragma unroll
    for (int off = 32; off > 0; off >>= 1) ssum += __shfl_xor(ssum, off, 64);
    av[tid] = e / ssum;
  }
  __syncthreads();
  for (int n = tid; n < 512; n += 256) {
    float a = 0.f;
    for (int m = 0; m < count; ++m)
      a += av[m] * hidden[((size_t)b*1024 + sidx[m]) * 512 + n];
    ctx[b*512 + n] = a;
  }
}

// ---------------------------------------------------------------------------
// out = ctx @ out_w^T + out_b via streaming split-bf16 MFMA (R7 core);
// bumped to 4 blocks/CU for latency hiding (LDS 33KB x 4 = 133KB fits).
// ---------------------------------------------------------------------------
__global__ __launch_bounds__(256, 4)
void out_k(const float* __restrict__ ctx, const float* __restrict__ out_w,
           const float* __restrict__ out_b, float* __restrict__ out)
{
  __shared__ __align__(16) ushort_t ctxH[32 * 520];
  __shared__ __align__(16) ushort_t ctxL[32 * 520];
  const int tid = threadIdx.x;
  const int wid = tid >> 6, lane = tid & 63;
  const int l16 = lane & 15, lkb = lane >> 4;

  {
    const int row = tid >> 3;
    const int c0 = (tid & 7) * 64;
    const float* src = ctx + row * 512 + c0;
    ushort_t* dh = ctxH + row * 520 + c0;
    ushort_t* dl = ctxL + row * 520 + c0;
#pragma unroll
    for (int u0 = 0; u0 < 64; u0 += 8) {
      const float4 a = *(const float4*)(src + u0);
      const float4 b = *(const float4*)(src + u0 + 4);
      u16x8 h, l;
      split8(a, b, h, l);
      *(u16x8*)(dh + u0) = h;
      *(u16x8*)(dl + u0) = l;
    }
  }
  __syncthreads();

  const int v = blockIdx.x * 64 + wid * 16 + l16;
  const float* wr = out_w + (size_t)v * 512 + lkb * 8;
  f32x4 acc0 = (f32x4){0.f, 0.f, 0.f, 0.f};
  f32x4 acc1 = (f32x4){0.f, 0.f, 0.f, 0.f};
#pragma unroll
  for (int ks = 0; ks < 16; ++ks) {
    const float4 wa = *(const float4*)(wr + ks * 32);
    const float4 wb = *(const float4*)(wr + ks * 32 + 4);
    u16x8 wh, wl;
    split8(wa, wb, wh, wl);
    const bf16x8 whb = (bf16x8)wh, wlb = (bf16x8)wl;
    const int co = ks * 32 + lkb * 8;
    const bf16x8 ch0 = *(const bf16x8*)(ctxH + l16 * 520 + co);
    const bf16x8 cl0 = *(const bf16x8*)(ctxL + l16 * 520 + co);
    const bf16x8 ch1 = *(const bf16x8*)(ctxH + (16 + l16) * 520 + co);
    const bf16x8 cl1 = *(const bf16x8*)(ctxL + (16 + l16) * 520 + co);
    acc0 = __builtin_amdgcn_mfma_f32_16x16x32_bf16(ch0, whb, acc0, 0, 0, 0);
    acc0 = __builtin_amdgcn_mfma_f32_16x16x32_bf16(cl0, whb, acc0, 0, 0, 0);
    acc0 = __builtin_amdgcn_mfma_f32_16x16x32_bf16(ch0, wlb, acc0, 0, 0, 0);
    acc1 = __builtin_amdgcn_mfma_f32_16x16x32_bf16(ch1, whb, acc1, 0, 0, 0);
    acc1 = __builtin_amdgcn_mfma_f32_16x16x32_bf16(cl1, whb, acc1, 0, 0, 0);
    acc1 = __builtin_amdgcn_mfma_f32_16x16x32_bf16(ch1, wlb, acc1, 0, 0, 0);
  }
  const float bv = out_b[v];
#pragma unroll
  for (int i = 0; i < 4; ++i) {
    out[(size_t)(lkb * 4 + i) * 32000 + v] = acc0[i] + bv;
    out[(size_t)(16 + lkb * 4 + i) * 32000 + v] = acc1[i] + bv;
  }
}

extern "C" void kernel_launch(void* const* d_in, const int* in_sizes, int n_in,
                              void* d_out, int out_size, void* d_ws, size_t ws_size,
                              hipStream_t stream)
{
  const int*   seq   = (const int*)d_in[0];
  const float* embed = (const float*)d_in[1];
  const float* w1    = (const float*)d_in[2];
  const float* b1    = (const float*)d_in[3];
  const float* w2    = (const float*)d_in[4];
  const float* b2    = (const float*)d_in[5];
  const float* ln_g  = (const float*)d_in[6];
  const float* ln_b  = (const float*)d_in[7];
  const float* wg_w  = (const float*)d_in[8];
  const float* wg_b  = (const float*)d_in[9];
  const float* q_w   = (const float*)d_in[10];
  const float* q_b   = (const float*)d_in[11];
  const float* out_w = (const float*)d_in[12];
  const float* out_b = (const float*)d_in[13];
  float* out = (float*)d_out;

  char* ws = (char*)d_ws;
  size_t off = 0;
  auto alloc = [&](size_t bytes) {
    void* p = ws + off;
    off += (bytes + 255) & ~(size_t)255;
    return p;
  };
  void* xA = alloc((size_t)32768 * 512 * 4);            // 67 MB
  ushort_t* Ahid = (ushort_t*)xA;
  ushort_t* Alid = Ahid + (size_t)32768 * 512;
  float* xbuf = (float*)xA;
  ushort_t* ff1h = (ushort_t*)alloc((size_t)32768 * 1024 * 2);  // 67 MB
  ushort_t* ff1l = (ushort_t*)alloc((size_t)32768 * 1024 * 2);  // 67 MB
  ushort_t* w1h = (ushort_t*)alloc((size_t)1024 * 512 * 2);
  ushort_t* w2h = (ushort_t*)alloc((size_t)512 * 1024 * 2);
  float* scores = (float*)alloc((size_t)32 * 1021 * 4);
  float* norms  = (float*)alloc((size_t)32 * 1021 * 4);
  int*   selidx = (int*)alloc((size_t)32 * 64 * 4);
  int*   selcnt = (int*)alloc((size_t)32 * 4);
  float* qbuf   = (float*)alloc((size_t)32 * 512 * 4);
  float* ctxb   = (float*)alloc((size_t)32 * 512 * 4);

  // fused pre-split (gather hi/lo + w1 hi + w2 hi)
  presplit<<<8704, 256, 0, stream>>>(seq, embed, Ahid, Alid,
                                     w1, w1h, w2, w2h);

  // FF1: relu(h @ w1^T + b1) -> ff1 hi/lo bf16  [32768,1024]  (2-term)
  gemmk<0><<<2048, 256, 0, stream>>>(Ahid, Alid, w1h, b1,
                                     nullptr, nullptr, ff1h, ff1l, nullptr,
                                     1024, 512);
  // FF2: ff1 @ w2^T + b2 + embed[seq] -> xbuf f32 [32768,512]  (2-term)
  gemmk<1><<<1024, 256, 0, stream>>>(ff1h, ff1l, w2h, b2,
                                     seq, embed, nullptr, nullptr, xbuf,
                                     512, 1024);
  lnscore_k<<<8192, 256, 0, stream>>>(xbuf, ln_g, ln_b, wg_w, wg_b, scores, norms);
  select_k<<<32, 256, 0, stream>>>(xbuf, scores, norms, selidx, selcnt);
  q_k<<<4096, 256, 0, stream>>>(xbuf, q_w, q_b, qbuf);
  attn_k<<<32, 256, 0, stream>>>(xbuf, qbuf, selidx, selcnt, ctxb);
  out_k<<<500, 256, 0, stream>>>(ctxb, out_w, out_b, out);
}

// Round 13
// 273.271 us; speedup vs baseline: 1.5388x; 1.1646x over previous
//
#include <hip/hip_runtime.h>
#include <math.h>

typedef unsigned short ushort_t;
typedef short bf16x8 __attribute__((ext_vector_type(8)));
typedef unsigned short u16x8 __attribute__((ext_vector_type(8)));
typedef float f32x4 __attribute__((ext_vector_type(4)));

__device__ __forceinline__ float wsum64(float v) {
#pragma unroll
  for (int off = 32; off > 0; off >>= 1) v += __shfl_xor(v, off, 64);
  return v;
}

__device__ __forceinline__ ushort_t f2bf(float x) {   // RNE f32->bf16
  unsigned u = __float_as_uint(x);
  return (ushort_t)((u + 0x7fffu + ((u >> 16) & 1u)) >> 16);
}
__device__ __forceinline__ float bf2f(ushort_t h) {
  return __uint_as_float(((unsigned)h) << 16);
}

__device__ __forceinline__ void split8(const float4 a, const float4 b,
                                       u16x8& h, u16x8& l) {
  h[0]=f2bf(a.x); l[0]=f2bf(a.x-bf2f(h[0]));
  h[1]=f2bf(a.y); l[1]=f2bf(a.y-bf2f(h[1]));
  h[2]=f2bf(a.z); l[2]=f2bf(a.z-bf2f(h[2]));
  h[3]=f2bf(a.w); l[3]=f2bf(a.w-bf2f(h[3]));
  h[4]=f2bf(b.x); l[4]=f2bf(b.x-bf2f(h[4]));
  h[5]=f2bf(b.y); l[5]=f2bf(b.y-bf2f(h[5]));
  h[6]=f2bf(b.z); l[6]=f2bf(b.z-bf2f(h[6]));
  h[7]=f2bf(b.w); l[7]=f2bf(b.w-bf2f(h[7]));
}

// async global(per-lane) -> LDS(wave-uniform base + lane*16B), 16B per lane
__device__ __forceinline__ void gl16(const void* g, const void* l) {
  __builtin_amdgcn_global_load_lds(
      (const __attribute__((address_space(1))) unsigned int*)g,
      (__attribute__((address_space(3))) unsigned int*)l, 16, 0, 0);
}

#define SBAR __builtin_amdgcn_sched_barrier(0)
#define BARRIER __builtin_amdgcn_s_barrier()
#define LGKM0 asm volatile("s_waitcnt lgkmcnt(0)" ::: "memory")
#define VMC0 asm volatile("s_waitcnt vmcnt(0)" ::: "memory")

// ---------------------------------------------------------------------------
// fused pre-split: gather-split of embed[seq] + w1 hi + w2 hi
// blocks [0,8192): gather rows; [8192,8448): w1; [8448,8704): w2
// ---------------------------------------------------------------------------
__global__ __launch_bounds__(256)
void presplit(const int* __restrict__ seq, const float* __restrict__ embed,
              ushort_t* __restrict__ Ah, ushort_t* __restrict__ Al,
              const float* __restrict__ w1, ushort_t* __restrict__ w1h,
              const float* __restrict__ w2, ushort_t* __restrict__ w2h)
{
  const int b = blockIdx.x, tid = threadIdx.x;
  if (b < 8192) {
    const int wid = tid >> 6, lane = tid & 63;
    const int row = b * 4 + wid;
    const float* src = embed + (size_t)seq[row] * 512 + lane * 8;
    const float4 a = *(const float4*)src;
    const float4 c = *(const float4*)(src + 4);
    u16x8 h, l;
    split8(a, c, h, l);
    *(u16x8*)(Ah + (size_t)row * 512 + lane * 8) = h;
    *(u16x8*)(Al + (size_t)row * 512 + lane * 8) = l;
  } else {
    const float* W;  ushort_t* Wh;  int i;
    if (b < 8448) { W = w1; Wh = w1h; i = (b - 8192) * 256 + tid; }
    else          { W = w2; Wh = w2h; i = (b - 8448) * 256 + tid; }
    const float4 a = *(const float4*)(W + (size_t)i * 8);
    const float4 c = *(const float4*)(W + (size_t)i * 8 + 4);
    u16x8 h, l;
    split8(a, c, h, l);
    *(u16x8*)(Wh + (size_t)i * 8) = h;
  }
}

// ---------------------------------------------------------------------------
// Split-bf16 MFMA GEMM, TERMS-parameterized:
//  TERMS=2: C ~= (Ah+Al).Bh^T  (virtual K'=2K; tile ts -> A-plane ts&1,
//           k-tile ts>>1; Bh_k shared by consecutive tiles -> L1/L2-hot)
//  TERMS=1: C ~= Ah.Bh^T       (plain bf16 GEMM, tile ts -> k-tile ts)
// 128x128 tile, 4 waves (2Mx2N), per-wave 64x64 = acc[4][4]. BK=64 virtual.
// LDS 64 KB = 2 dbuf x (A 16KB + B 16KB) -> 2 blocks/CU (R8/R11 core).
// A-panel-grouping swizzle: blocks sharing an A panel on the same XCD.
// Rows 128 B (8 chunks x 16 B), chunk-XOR (row&7) via pre-swizzled source.
// EPI 0: +bias, relu -> Oh bf16 hi only (per-wave LDS bounce, coalesced 8B).
// EPI 1: +bias + embed[seq[row]] -> f32.
// ---------------------------------------------------------------------------
template<int EPI, int TERMS>
__global__ __launch_bounds__(256, 2)
void gemmk(const ushort_t* __restrict__ Ah, const ushort_t* __restrict__ Al,
           const ushort_t* __restrict__ Bh,
           const float* __restrict__ bias,
           const int* __restrict__ seq, const float* __restrict__ embed,
           ushort_t* __restrict__ Oh,
           float* __restrict__ Of, int N, int K)
{
  __shared__ __align__(16) ushort_t lds[32768];   // 64 KB
  const int tid = threadIdx.x;
  const int numN = N >> 7;
  const int xg = blockIdx.x & 7, jg = blockIdx.x >> 3;
  const int mt = xg + 8 * (jg / numN);
  const int nt = jg - (jg / numN) * numN;
  const int m0 = mt << 7;
  const int n0 = nt << 7;
  const int wid = tid >> 6, lane = tid & 63;
  const int wm = wid >> 1, wn = wid & 1;
  const int l16 = lane & 15, lkb = lane >> 4;

  const int tpt = K >> 6;       // real-K tiles (BK=64)
  const int NT  = TERMS * tpt;  // virtual tiles
  const int NI  = NT >> 1;      // iterations (2 tiles each)

  int offA[4], offB[4];         // element offsets (row*K + swizzled col)
#pragma unroll
  for (int j = 0; j < 4; ++j) {
    const int cj = tid + j * 256;
    const int row = cj >> 3;
    const int sc = ((cj & 7) ^ (row & 7)) << 3;
    offA[j] = (m0 + row) * K + sc;
    offB[j] = (n0 + row) * K + sc;
  }

  auto stageA = [&](int ts, int buf) {
    const ushort_t* p;
    if (TERMS == 2) p = ((ts & 1) ? Al : Ah) + ((ts >> 1) << 6);
    else            p = Ah + (ts << 6);
    ushort_t* base = lds + buf * 16384 + wid * 512;
#pragma unroll
    for (int j = 0; j < 4; ++j) gl16(p + offA[j], base + j * 2048);
  };
  auto stageB = [&](int ts, int buf) {
    const ushort_t* p;
    if (TERMS == 2) p = Bh + ((ts >> 1) << 6);
    else            p = Bh + (ts << 6);
    ushort_t* base = lds + buf * 16384 + 8192 + wid * 512;
#pragma unroll
    for (int j = 0; j < 4; ++j) gl16(p + offB[j], base + j * 2048);
  };

  bf16x8 fa[4], fb[4];
  f32x4 acc[4][4];
#pragma unroll
  for (int m = 0; m < 4; ++m)
#pragma unroll
    for (int n = 0; n < 4; ++n) acc[m][n] = (f32x4){0.f, 0.f, 0.f, 0.f};

  const int swz = l16 & 7;
  auto ldfrag = [&](int buf, int ks) {
    const int kc = ks * 4;
    const ushort_t* b0 = lds + buf * 16384;
#pragma unroll
    for (int m = 0; m < 4; ++m)
      fa[m] = *(const bf16x8*)(b0 + (wm * 64 + m * 16 + l16) * 64
                                  + (((kc + lkb) ^ swz) << 3));
#pragma unroll
    for (int nf = 0; nf < 4; ++nf)
      fb[nf] = *(const bf16x8*)(b0 + 8192 + (wn * 64 + nf * 16 + l16) * 64
                                  + (((kc + lkb) ^ swz) << 3));
  };
  auto mfma16 = [&]() {
    __builtin_amdgcn_s_setprio(1);
#pragma unroll
    for (int m = 0; m < 4; ++m)
#pragma unroll
      for (int nf = 0; nf < 4; ++nf)
        acc[m][nf] = __builtin_amdgcn_mfma_f32_16x16x32_bf16(
            fa[m], fb[nf], acc[m][nf], 0, 0, 0);
    __builtin_amdgcn_s_setprio(0);
  };

  // prologue: tile 0 staged + verified
  stageA(0, 0); stageB(0, 0);
  VMC0; BARRIER; SBAR;

  for (int i = 0; i < NI; ++i) {
    const int b = 2 * i + 1;
    const bool more = (i + 1 < NI);
    // ph0: tile 2i, ks0
    ldfrag(0, 0); stageA(b, 1); LGKM0; SBAR; mfma16();
    // ph1: tile 2i, ks1; verify tile 2i+1 before its reads
    ldfrag(0, 1); stageB(b, 1); LGKM0; SBAR; mfma16();
    VMC0; BARRIER; SBAR;
    // ph2: tile 2i+1, ks0
    ldfrag(1, 0); if (more) stageA(b + 1, 0); LGKM0; SBAR; mfma16();
    // ph3: tile 2i+1, ks1; verify tile 2i+2
    ldfrag(1, 1); if (more) stageB(b + 1, 0); LGKM0; SBAR; mfma16();
    VMC0; BARRIER; SBAR;
  }

  // epilogue: wave tile 64x64 at rows m0+wm*64, cols n0+wn*64.
  // C/D frag: col=l16 (n), row=lkb*4+ii (m)
  if (EPI == 0) {
    ushort_t* pw = lds + wid * 4096;   // 8 KB per wave (u16 elems)
    float bv[4];
#pragma unroll
    for (int nf = 0; nf < 4; ++nf) bv[nf] = bias[n0 + wn * 64 + nf * 16 + l16];
#pragma unroll
    for (int m = 0; m < 4; ++m)
#pragma unroll
      for (int nf = 0; nf < 4; ++nf)
#pragma unroll
        for (int ii = 0; ii < 4; ++ii) {
          float v = fmaxf(acc[m][nf][ii] + bv[nf], 0.f);
          const int row = m * 16 + lkb * 4 + ii;
          pw[row * 64 + nf * 16 + l16] = f2bf(v);
        }
#pragma unroll
    for (int p = 0; p < 8; ++p) {
      const int idx = p * 512 + lane * 8;
      const int row = idx >> 6, col = idx & 63;
      const u16x8 w = *(const u16x8*)(pw + idx);
      const size_t go = (size_t)(m0 + wm * 64 + row) * N + (n0 + wn * 64 + col);
      *(u16x8*)(Oh + go) = w;
    }
  } else {
#pragma unroll
    for (int nf = 0; nf < 4; ++nf) {
      const int col = n0 + wn * 64 + nf * 16 + l16;
      const float bvv = bias[col];
#pragma unroll
      for (int m = 0; m < 4; ++m) {
        const int rbase = m0 + wm * 64 + m * 16 + lkb * 4;
#pragma unroll
        for (int ii = 0; ii < 4; ++ii) {
          const int row = rbase + ii;
          float v = acc[m][nf][ii] + bvv;
          v += embed[(size_t)seq[row] * 512 + col];
          Of[(size_t)row * N + col] = v;
        }
      }
    }
  }
}

// in-place LayerNorm + fused gate score + L2 norm; one wave per 512-elem row
__global__ __launch_bounds__(256)
void lnscore_k(float* __restrict__ x, const float* __restrict__ g,
               const float* __restrict__ bt, const float* __restrict__ wg_w,
               const float* __restrict__ wg_b, float* __restrict__ scores,
               float* __restrict__ norms)
{
  const int wid = threadIdx.x >> 6, lane = threadIdx.x & 63;
  const int row = blockIdx.x * 4 + wid;
  float* xr = x + (size_t)row * 512;
  const float4 v0 = *(const float4*)(xr + lane*4);
  const float4 v1 = *(const float4*)(xr + 256 + lane*4);
  float s = v0.x+v0.y+v0.z+v0.w + v1.x+v1.y+v1.z+v1.w;
  s = wsum64(s);
  const float mu = s * (1.f/512.f);
  float ss = (v0.x-mu)*(v0.x-mu) + (v0.y-mu)*(v0.y-mu)
           + (v0.z-mu)*(v0.z-mu) + (v0.w-mu)*(v0.w-mu)
           + (v1.x-mu)*(v1.x-mu) + (v1.y-mu)*(v1.y-mu)
           + (v1.z-mu)*(v1.z-mu) + (v1.w-mu)*(v1.w-mu);
  ss = wsum64(ss);
  const float inv = 1.f / sqrtf(ss * (1.f/512.f) + 1e-5f);
  const float4 g0 = *(const float4*)(g + lane*4);
  const float4 g1 = *(const float4*)(g + 256 + lane*4);
  const float4 c0 = *(const float4*)(bt + lane*4);
  const float4 c1 = *(const float4*)(bt + 256 + lane*4);
  float4 o0, o1;
  o0.x = (v0.x-mu)*inv*g0.x + c0.x;  o0.y = (v0.y-mu)*inv*g0.y + c0.y;
  o0.z = (v0.z-mu)*inv*g0.z + c0.z;  o0.w = (v0.w-mu)*inv*g0.w + c0.w;
  o1.x = (v1.x-mu)*inv*g1.x + c1.x;  o1.y = (v1.y-mu)*inv*g1.y + c1.y;
  o1.z = (v1.z-mu)*inv*g1.z + c1.z;  o1.w = (v1.w-mu)*inv*g1.w + c1.w;
  *(float4*)(xr + lane*4) = o0;
  *(float4*)(xr + 256 + lane*4) = o1;

  const float4 q0 = *(const float4*)(wg_w + lane*4);
  const float4 q1 = *(const float4*)(wg_w + 256 + lane*4);
  float d = o0.x*q0.x + o0.y*q0.y + o0.z*q0.z + o0.w*q0.w
          + o1.x*q1.x + o1.y*q1.y + o1.z*q1.z + o1.w*q1.w;
  float n2 = o0.x*o0.x + o0.y*o0.y + o0.z*o0.z + o0.w*o0.w
           + o1.x*o1.x + o1.y*o1.y + o1.z*o1.z + o1.w*o1.w;
  d = wsum64(d); n2 = wsum64(n2);
  const int b = row >> 10, t = row & 1023;
  if (lane == 0 && t < 1021) {
    scores[b * 1021 + t] = d + wg_b[0];
    norms[b * 1021 + t] = sqrtf(n2);
  }
}

// ---------------------------------------------------------------------------
// Greedy score-ranked selection with cosine dedup; one block per batch row.
// ---------------------------------------------------------------------------
__global__ __launch_bounds__(256, 1)
void select_k(const float* __restrict__ hidden, const float* __restrict__ scores,
              const float* __restrict__ norms, int* __restrict__ selidx_g,
              int* __restrict__ selcnt_g)
{
  __shared__ __align__(16) ushort_t allH[128 * 520];     // 133120 B (keys alias)
  __shared__ ushort_t simS[64 * 128];
  __shared__ ushort_t sortedIdx[1024];
  __shared__ ushort_t selT[64];
  __shared__ ushort_t newPos[64];
  __shared__ int s_count, s_nacc;

  const int b = blockIdx.x, tid = threadIdx.x;
  const int wid = tid >> 6, lane = tid & 63;
  const int l16 = lane & 15, lkb = lane >> 4;

  unsigned long long* keys = (unsigned long long*)allH;
  for (int i = tid; i < 1024; i += 256) {
    const float s = (i < 1021) ? scores[b * 1021 + i] : -INFINITY;
    const unsigned u = __float_as_uint(s);
    const unsigned ms = (u & 0x80000000u) ? ~u : (u | 0x80000000u);
    keys[i] = ((unsigned long long)(~ms) << 32) | (unsigned)i;
  }
  __syncthreads();
  for (int k = 2; k <= 1024; k <<= 1) {
    for (int j = k >> 1; j > 0; j >>= 1) {
      for (int i = tid; i < 1024; i += 256) {
        const int ixj = i ^ j;
        if (ixj > i) {
          const unsigned long long a = keys[i], c = keys[ixj];
          const bool up = ((i & k) == 0);
          if ((a > c) == up) { keys[i] = c; keys[ixj] = a; }
        }
      }
      __syncthreads();
    }
  }
  for (int i = tid; i < 1024; i += 256)
    sortedIdx[i] = (ushort_t)(keys[i] & 0xffffu);
  if (tid == 0) s_count = 0;
  __syncthreads();

  int p = 0;
  while (true) {
    const int count = s_count;
    if (count >= 64 || p >= 1021) break;
    const int C = min(64, 1021 - p);

    {
      const int r = tid >> 2;
      const int seg = (tid & 3) * 128;
      if (r < C) {
        const int t = sortedIdx[p + r];
        const float rn = 1.f / fmaxf(norms[b * 1021 + t], 1e-12f);
        const float* src = hidden + ((size_t)b * 1024 + t) * 512 + seg;
        ushort_t* dst = allH + (64 + r) * 520 + seg;
#pragma unroll
        for (int u0 = 0; u0 < 128; u0 += 8) {
          const float4 x = *(const float4*)(src + u0);
          const float4 y = *(const float4*)(src + u0 + 4);
          u16x8 o;
          o[0] = f2bf(x.x * rn); o[1] = f2bf(x.y * rn);
          o[2] = f2bf(x.z * rn); o[3] = f2bf(x.w * rn);
          o[4] = f2bf(y.x * rn); o[5] = f2bf(y.y * rn);
          o[6] = f2bf(y.z * rn); o[7] = f2bf(y.w * rn);
          *(u16x8*)(dst + u0) = o;
        }
      }
    }
    __syncthreads();

    {
      f32x4 acc[8];
#pragma unroll
      for (int t = 0; t < 8; ++t) acc[t] = (f32x4){0.f, 0.f, 0.f, 0.f};
      const ushort_t* Abase = allH + (64 + (wid << 4) + l16) * 520;
#pragma unroll
      for (int ks = 0; ks < 16; ++ks) {
        const bf16x8 a = *(const bf16x8*)(Abase + ks * 32 + lkb * 8);
#pragma unroll
        for (int t = 0; t < 8; ++t) {
          const bf16x8 bb = *(const bf16x8*)(allH + ((t << 4) + l16) * 520 + ks * 32 + lkb * 8);
          acc[t] = __builtin_amdgcn_mfma_f32_16x16x32_bf16(a, bb, acc[t], 0, 0, 0);
        }
      }
#pragma unroll
      for (int t = 0; t < 8; ++t)
#pragma unroll
        for (int ii = 0; ii < 4; ++ii) {
          const int ri = (wid << 4) + lkb * 4 + ii;
          simS[ri * 128 + (t << 4) + l16] = f2bf(acc[t][ii]);
        }
    }
    __syncthreads();

    if (wid == 0) {
      unsigned long long accMask = 0ull;
      int nacc = 0;
      for (int i = 0; i < C; ++i) {
        float v = -INFINITY;
        if (lane < count) v = bf2f(simS[i * 128 + lane]);
        if ((accMask >> lane) & 1ull) v = fmaxf(v, bf2f(simS[i * 128 + 64 + lane]));
#pragma unroll
        for (int off = 32; off > 0; off >>= 1) v = fmaxf(v, __shfl_xor(v, off, 64));
        const int total = count + nacc;
        const bool ok = (total == 0) || (v <= 0.8f);
        if (total < 64 && ok) {
          if (lane == 0) { selT[total] = sortedIdx[p + i]; newPos[nacc] = (ushort_t)i; }
          accMask |= (1ull << i);
          ++nacc;
          if (total + 1 == 64) break;
        }
      }
      if (lane == 0) { s_nacc = nacc; s_count = count + nacc; }
    }
    __syncthreads();

    {
      const int nacc = s_nacc;
      for (int a = wid; a < nacc; a += 4) {
        const int srcrow = 64 + (int)newPos[a];
        const int dstrow = count + a;
        const u16x8 val = *(const u16x8*)(allH + srcrow * 520 + lane * 8);
        *(u16x8*)(allH + dstrow * 520 + lane * 8) = val;
      }
    }
    p += C;
    __syncthreads();
  }

  __syncthreads();
  if (tid < 64) selidx_g[b * 64 + tid] = (tid < s_count) ? (int)selT[tid] : 0;
  if (tid == 0) selcnt_g[b] = s_count;
}

// q = hidden[:, T-2, :] @ q_w^T + q_b ; one wave per output element
__global__ __launch_bounds__(256)
void q_k(const float* __restrict__ hidden, const float* __restrict__ q_w,
         const float* __restrict__ q_b, float* __restrict__ qv)
{
  const int wid = threadIdx.x >> 6, lane = threadIdx.x & 63;
  const int o = blockIdx.x * 4 + wid;
  const int b = o >> 9, n = o & 511;
  const float* hr = hidden + ((size_t)b*1024 + 1022) * 512;
  const float* wr = q_w + (size_t)n * 512;
  const float4 h0 = *(const float4*)(hr + lane*4);
  const float4 h1 = *(const float4*)(hr + 256 + lane*4);
  const float4 w0 = *(const float4*)(wr + lane*4);
  const float4 w1 = *(const float4*)(wr + 256 + lane*4);
  float d = h0.x*w0.x + h0.y*w0.y + h0.z*w0.z + h0.w*w0.w
          + h1.x*w1.x + h1.y*w1.y + h1.z*w1.z + h1.w*w1.w;
  d = wsum64(d);
  if (lane == 0) qv[o] = d + q_b[n];
}

// masked softmax attention over selected memory; one block per batch
__global__ __launch_bounds__(256)
void attn_k(const float* __restrict__ hidden, const float* __restrict__ qv,
            const int* __restrict__ selidx_g, const int* __restrict__ selcnt_g,
            float* __restrict__ ctx)
{
  const int b = blockIdx.x, tid = threadIdx.x;
  const int wid = tid >> 6, lane = tid & 63;
  __shared__ float qs[512];
  __shared__ int sidx[64];
  __shared__ float sv[64];
  __shared__ float av[64];
  const int count = selcnt_g[b];
  for (int i = tid; i < 512; i += 256) qs[i] = qv[b*512 + i];
  if (tid < 64) sidx[tid] = selidx_g[b*64 + tid];
  __syncthreads();
  for (int m = wid; m < 64; m += 4) {
    float sval = -1e9f;
    if (m < count) {
      const float* hr = hidden + ((size_t)b*1024 + sidx[m]) * 512;
      const float4 a0 = *(const float4*)(hr + lane*4);
      const float4 a1 = *(const float4*)(hr + 256 + lane*4);
      const float4 q0 = *(const float4*)(&qs[lane*4]);
      const float4 q1 = *(const float4*)(&qs[256 + lane*4]);
      float d = a0.x*q0.x + a0.y*q0.y + a0.z*q0.z + a0.w*q0.w
              + a1.x*q1.x + a1.y*q1.y + a1.z*q1.z + a1.w*q1.w;
      d = wsum64(d);
      sval = d;
    }
    if (lane == 0) sv[m] = sval;
  }
  __syncthreads();
  if (tid < 64) {
    const float v = sv[tid];
    float mx = v;
#pragma unroll
    for (int off = 32; off > 0; off >>= 1) mx = fmaxf(mx, __shfl_xor(mx, off, 64));
    const float e = expf(v - mx);
    float ssum = e;
#pragma unroll
    for (int off = 32; off > 0; off >>= 1) ssum += __shfl_xor(ssum, off, 64);
    av[tid] = e / ssum;
  }
  __syncthreads();
  for (int n = tid; n < 512; n += 256) {
    float a = 0.f;
    for (int m = 0; m < count; ++m)
      a += av[m] * hidden[((size_t)b*1024 + sidx[m]) * 512 + n];
    ctx[b*512 + n] = a;
  }
}

// ---------------------------------------------------------------------------
// out = ctx @ out_w^T + out_b via streaming split-bf16 MFMA (R7 core, 4/CU).
// ---------------------------------------------------------------------------
__global__ __launch_bounds__(256, 4)
void out_k(const float* __restrict__ ctx, const float* __restrict__ out_w,
           const float* __restrict__ out_b, float* __restrict__ out)
{
  __shared__ __align__(16) ushort_t ctxH[32 * 520];
  __shared__ __align__(16) ushort_t ctxL[32 * 520];
  const int tid = threadIdx.x;
  const int wid = tid >> 6, lane = tid & 63;
  const int l16 = lane & 15, lkb = lane >> 4;

  {
    const int row = tid >> 3;
    const int c0 = (tid & 7) * 64;
    const float* src = ctx + row * 512 + c0;
    ushort_t* dh = ctxH + row * 520 + c0;
    ushort_t* dl = ctxL + row * 520 + c0;
#pragma unroll
    for (int u0 = 0; u0 < 64; u0 += 8) {
      const float4 a = *(const float4*)(src + u0);
      const float4 b = *(const float4*)(src + u0 + 4);
      u16x8 h, l;
      split8(a, b, h, l);
      *(u16x8*)(dh + u0) = h;
      *(u16x8*)(dl + u0) = l;
    }
  }
  __syncthreads();

  const int v = blockIdx.x * 64 + wid * 16 + l16;
  const float* wr = out_w + (size_t)v * 512 + lkb * 8;
  f32x4 acc0 = (f32x4){0.f, 0.f, 0.f, 0.f};
  f32x4 acc1 = (f32x4){0.f, 0.f, 0.f, 0.f};
#pragma unroll
  for (int ks = 0; ks < 16; ++ks) {
    const float4 wa = *(const float4*)(wr + ks * 32);
    const float4 wb = *(const float4*)(wr + ks * 32 + 4);
    u16x8 wh, wl;
    split8(wa, wb, wh, wl);
    const bf16x8 whb = (bf16x8)wh, wlb = (bf16x8)wl;
    const int co = ks * 32 + lkb * 8;
    const bf16x8 ch0 = *(const bf16x8*)(ctxH + l16 * 520 + co);
    const bf16x8 cl0 = *(const bf16x8*)(ctxL + l16 * 520 + co);
    const bf16x8 ch1 = *(const bf16x8*)(ctxH + (16 + l16) * 520 + co);
    const bf16x8 cl1 = *(const bf16x8*)(ctxL + (16 + l16) * 520 + co);
    acc0 = __builtin_amdgcn_mfma_f32_16x16x32_bf16(ch0, whb, acc0, 0, 0, 0);
    acc0 = __builtin_amdgcn_mfma_f32_16x16x32_bf16(cl0, whb, acc0, 0, 0, 0);
    acc0 = __builtin_amdgcn_mfma_f32_16x16x32_bf16(ch0, wlb, acc0, 0, 0, 0);
    acc1 = __builtin_amdgcn_mfma_f32_16x16x32_bf16(ch1, whb, acc1, 0, 0, 0);
    acc1 = __builtin_amdgcn_mfma_f32_16x16x32_bf16(cl1, whb, acc1, 0, 0, 0);
    acc1 = __builtin_amdgcn_mfma_f32_16x16x32_bf16(ch1, wlb, acc1, 0, 0, 0);
  }
  const float bv = out_b[v];
#pragma unroll
  for (int i = 0; i < 4; ++i) {
    out[(size_t)(lkb * 4 + i) * 32000 + v] = acc0[i] + bv;
    out[(size_t)(16 + lkb * 4 + i) * 32000 + v] = acc1[i] + bv;
  }
}

extern "C" void kernel_launch(void* const* d_in, const int* in_sizes, int n_in,
                              void* d_out, int out_size, void* d_ws, size_t ws_size,
                              hipStream_t stream)
{
  const int*   seq   = (const int*)d_in[0];
  const float* embed = (const float*)d_in[1];
  const float* w1    = (const float*)d_in[2];
  const float* b1    = (const float*)d_in[3];
  const float* w2    = (const float*)d_in[4];
  const float* b2    = (const float*)d_in[5];
  const float* ln_g  = (const float*)d_in[6];
  const float* ln_b  = (const float*)d_in[7];
  const float* wg_w  = (const float*)d_in[8];
  const float* wg_b  = (const float*)d_in[9];
  const float* q_w   = (const float*)d_in[10];
  const float* q_b   = (const float*)d_in[11];
  const float* out_w = (const float*)d_in[12];
  const float* out_b = (const float*)d_in[13];
  float* out = (float*)d_out;

  char* ws = (char*)d_ws;
  size_t off = 0;
  auto alloc = [&](size_t bytes) {
    void* p = ws + off;
    off += (bytes + 255) & ~(size_t)255;
    return p;
  };
  void* xA = alloc((size_t)32768 * 512 * 4);            // 67 MB
  ushort_t* Ahid = (ushort_t*)xA;
  ushort_t* Alid = Ahid + (size_t)32768 * 512;
  float* xbuf = (float*)xA;
  ushort_t* ff1h = (ushort_t*)alloc((size_t)32768 * 1024 * 2);  // 67 MB
  ushort_t* w1h = (ushort_t*)alloc((size_t)1024 * 512 * 2);
  ushort_t* w2h = (ushort_t*)alloc((size_t)512 * 1024 * 2);
  float* scores = (float*)alloc((size_t)32 * 1021 * 4);
  float* norms  = (float*)alloc((size_t)32 * 1021 * 4);
  int*   selidx = (int*)alloc((size_t)32 * 64 * 4);
  int*   selcnt = (int*)alloc((size_t)32 * 4);
  float* qbuf   = (float*)alloc((size_t)32 * 512 * 4);
  float* ctxb   = (float*)alloc((size_t)32 * 512 * 4);

  // fused pre-split (gather hi/lo + w1 hi + w2 hi)
  presplit<<<8704, 256, 0, stream>>>(seq, embed, Ahid, Alid,
                                     w1, w1h, w2, w2h);

  // FF1: relu(h @ w1^T + b1) -> ff1 hi bf16  [32768,1024]  (2-term A)
  gemmk<0, 2><<<2048, 256, 0, stream>>>(Ahid, Alid, w1h, b1,
                                        nullptr, nullptr, ff1h, nullptr,
                                        1024, 512);
  // FF2: ff1h @ w2h^T + b2 + embed[seq] -> xbuf f32 [32768,512]  (1-term)
  gemmk<1, 1><<<1024, 256, 0, stream>>>(ff1h, ff1h, w2h, b2,
                                        seq, embed, nullptr, xbuf,
                                        512, 1024);
  lnscore_k<<<8192, 256, 0, stream>>>(xbuf, ln_g, ln_b, wg_w, wg_b, scores, norms);
  select_k<<<32, 256, 0, stream>>>(xbuf, scores, norms, selidx, selcnt);
  q_k<<<4096, 256, 0, stream>>>(xbuf, q_w, q_b, qbuf);
  attn_k<<<32, 256, 0, stream>>>(xbuf, qbuf, selidx, selcnt, ctxb);
  out_k<<<500, 256, 0, stream>>>(ctxb, out_w, out_b, out);
}

// Round 14
// 262.158 us; speedup vs baseline: 1.6040x; 1.0424x over previous
//
#include <hip/hip_runtime.h>
#include <math.h>

typedef unsigned short ushort_t;
typedef short bf16x8 __attribute__((ext_vector_type(8)));
typedef unsigned short u16x8 __attribute__((ext_vector_type(8)));
typedef float f32x4 __attribute__((ext_vector_type(4)));

__device__ __forceinline__ float wsum64(float v) {
#pragma unroll
  for (int off = 32; off > 0; off >>= 1) v += __shfl_xor(v, off, 64);
  return v;
}

__device__ __forceinline__ ushort_t f2bf(float x) {   // RNE f32->bf16
  unsigned u = __float_as_uint(x);
  return (ushort_t)((u + 0x7fffu + ((u >> 16) & 1u)) >> 16);
}
__device__ __forceinline__ float bf2f(ushort_t h) {
  return __uint_as_float(((unsigned)h) << 16);
}

__device__ __forceinline__ void split8(const float4 a, const float4 b,
                                       u16x8& h, u16x8& l) {
  h[0]=f2bf(a.x); l[0]=f2bf(a.x-bf2f(h[0]));
  h[1]=f2bf(a.y); l[1]=f2bf(a.y-bf2f(h[1]));
  h[2]=f2bf(a.z); l[2]=f2bf(a.z-bf2f(h[2]));
  h[3]=f2bf(a.w); l[3]=f2bf(a.w-bf2f(h[3]));
  h[4]=f2bf(b.x); l[4]=f2bf(b.x-bf2f(h[4]));
  h[5]=f2bf(b.y); l[5]=f2bf(b.y-bf2f(h[5]));
  h[6]=f2bf(b.z); l[6]=f2bf(b.z-bf2f(h[6]));
  h[7]=f2bf(b.w); l[7]=f2bf(b.w-bf2f(h[7]));
}

// async global(per-lane) -> LDS(wave-uniform base + lane*16B), 16B per lane
__device__ __forceinline__ void gl16(const void* g, const void* l) {
  __builtin_amdgcn_global_load_lds(
      (const __attribute__((address_space(1))) unsigned int*)g,
      (__attribute__((address_space(3))) unsigned int*)l, 16, 0, 0);
}

#define SBAR __builtin_amdgcn_sched_barrier(0)
#define BARRIER __builtin_amdgcn_s_barrier()
#define LGKM0 asm volatile("s_waitcnt lgkmcnt(0)" ::: "memory")
#define VMC0 asm volatile("s_waitcnt vmcnt(0)" ::: "memory")

// ---------------------------------------------------------------------------
// fused pre-split: gather-split of embed[seq] + w1 hi + w2 hi
// ---------------------------------------------------------------------------
__global__ __launch_bounds__(256)
void presplit(const int* __restrict__ seq, const float* __restrict__ embed,
              ushort_t* __restrict__ Ah, ushort_t* __restrict__ Al,
              const float* __restrict__ w1, ushort_t* __restrict__ w1h,
              const float* __restrict__ w2, ushort_t* __restrict__ w2h)
{
  const int b = blockIdx.x, tid = threadIdx.x;
  if (b < 8192) {
    const int wid = tid >> 6, lane = tid & 63;
    const int row = b * 4 + wid;
    const float* src = embed + (size_t)seq[row] * 512 + lane * 8;
    const float4 a = *(const float4*)src;
    const float4 c = *(const float4*)(src + 4);
    u16x8 h, l;
    split8(a, c, h, l);
    *(u16x8*)(Ah + (size_t)row * 512 + lane * 8) = h;
    *(u16x8*)(Al + (size_t)row * 512 + lane * 8) = l;
  } else {
    const float* W;  ushort_t* Wh;  int i;
    if (b < 8448) { W = w1; Wh = w1h; i = (b - 8192) * 256 + tid; }
    else          { W = w2; Wh = w2h; i = (b - 8448) * 256 + tid; }
    const float4 a = *(const float4*)(W + (size_t)i * 8);
    const float4 c = *(const float4*)(W + (size_t)i * 8 + 4);
    u16x8 h, l;
    split8(a, c, h, l);
    *(u16x8*)(Wh + (size_t)i * 8) = h;
  }
}

// ---------------------------------------------------------------------------
// Split-bf16 MFMA GEMM (R11/R13 core), TERMS-parameterized.
// EPI 0: +bias, relu -> Oh bf16 (per-wave LDS bounce, coalesced 16B stores).
// EPI 1: +bias -> f32 via per-wave LDS bounce (coalesced 16B stores; residual
//        moved to lnscore where it's a coalesced full-row read).
// ---------------------------------------------------------------------------
template<int EPI, int TERMS>
__global__ __launch_bounds__(256, 2)
void gemmk(const ushort_t* __restrict__ Ah, const ushort_t* __restrict__ Al,
           const ushort_t* __restrict__ Bh,
           const float* __restrict__ bias,
           ushort_t* __restrict__ Oh,
           float* __restrict__ Of, int N, int K)
{
  __shared__ __align__(16) ushort_t lds[32768];   // 64 KB
  const int tid = threadIdx.x;
  const int numN = N >> 7;
  const int xg = blockIdx.x & 7, jg = blockIdx.x >> 3;
  const int mt = xg + 8 * (jg / numN);
  const int nt = jg - (jg / numN) * numN;
  const int m0 = mt << 7;
  const int n0 = nt << 7;
  const int wid = tid >> 6, lane = tid & 63;
  const int wm = wid >> 1, wn = wid & 1;
  const int l16 = lane & 15, lkb = lane >> 4;

  const int tpt = K >> 6;       // real-K tiles (BK=64)
  const int NT  = TERMS * tpt;  // virtual tiles
  const int NI  = NT >> 1;      // iterations (2 tiles each)

  int offA[4], offB[4];
#pragma unroll
  for (int j = 0; j < 4; ++j) {
    const int cj = tid + j * 256;
    const int row = cj >> 3;
    const int sc = ((cj & 7) ^ (row & 7)) << 3;
    offA[j] = (m0 + row) * K + sc;
    offB[j] = (n0 + row) * K + sc;
  }

  auto stageA = [&](int ts, int buf) {
    const ushort_t* p;
    if (TERMS == 2) p = ((ts & 1) ? Al : Ah) + ((ts >> 1) << 6);
    else            p = Ah + (ts << 6);
    ushort_t* base = lds + buf * 16384 + wid * 512;
#pragma unroll
    for (int j = 0; j < 4; ++j) gl16(p + offA[j], base + j * 2048);
  };
  auto stageB = [&](int ts, int buf) {
    const ushort_t* p;
    if (TERMS == 2) p = Bh + ((ts >> 1) << 6);
    else            p = Bh + (ts << 6);
    ushort_t* base = lds + buf * 16384 + 8192 + wid * 512;
#pragma unroll
    for (int j = 0; j < 4; ++j) gl16(p + offB[j], base + j * 2048);
  };

  bf16x8 fa[4], fb[4];
  f32x4 acc[4][4];
#pragma unroll
  for (int m = 0; m < 4; ++m)
#pragma unroll
    for (int n = 0; n < 4; ++n) acc[m][n] = (f32x4){0.f, 0.f, 0.f, 0.f};

  const int swz = l16 & 7;
  auto ldfrag = [&](int buf, int ks) {
    const int kc = ks * 4;
    const ushort_t* b0 = lds + buf * 16384;
#pragma unroll
    for (int m = 0; m < 4; ++m)
      fa[m] = *(const bf16x8*)(b0 + (wm * 64 + m * 16 + l16) * 64
                                  + (((kc + lkb) ^ swz) << 3));
#pragma unroll
    for (int nf = 0; nf < 4; ++nf)
      fb[nf] = *(const bf16x8*)(b0 + 8192 + (wn * 64 + nf * 16 + l16) * 64
                                  + (((kc + lkb) ^ swz) << 3));
  };
  auto mfma16 = [&]() {
    __builtin_amdgcn_s_setprio(1);
#pragma unroll
    for (int m = 0; m < 4; ++m)
#pragma unroll
      for (int nf = 0; nf < 4; ++nf)
        acc[m][nf] = __builtin_amdgcn_mfma_f32_16x16x32_bf16(
            fa[m], fb[nf], acc[m][nf], 0, 0, 0);
    __builtin_amdgcn_s_setprio(0);
  };

  stageA(0, 0); stageB(0, 0);
  VMC0; BARRIER; SBAR;

  for (int i = 0; i < NI; ++i) {
    const int b = 2 * i + 1;
    const bool more = (i + 1 < NI);
    ldfrag(0, 0); stageA(b, 1); LGKM0; SBAR; mfma16();
    ldfrag(0, 1); stageB(b, 1); LGKM0; SBAR; mfma16();
    VMC0; BARRIER; SBAR;
    ldfrag(1, 0); if (more) stageA(b + 1, 0); LGKM0; SBAR; mfma16();
    ldfrag(1, 1); if (more) stageB(b + 1, 0); LGKM0; SBAR; mfma16();
    VMC0; BARRIER; SBAR;
  }

  // epilogue: wave tile 64x64 at rows m0+wm*64, cols n0+wn*64.
  // C/D frag: col=l16 (n), row=lkb*4+ii (m)
  if (EPI == 0) {
    ushort_t* pw = lds + wid * 4096;   // 8 KB per wave (u16)
    float bv[4];
#pragma unroll
    for (int nf = 0; nf < 4; ++nf) bv[nf] = bias[n0 + wn * 64 + nf * 16 + l16];
#pragma unroll
    for (int m = 0; m < 4; ++m)
#pragma unroll
      for (int nf = 0; nf < 4; ++nf)
#pragma unroll
        for (int ii = 0; ii < 4; ++ii) {
          float v = fmaxf(acc[m][nf][ii] + bv[nf], 0.f);
          const int row = m * 16 + lkb * 4 + ii;
          pw[row * 64 + nf * 16 + l16] = f2bf(v);
        }
#pragma unroll
    for (int p = 0; p < 8; ++p) {
      const int idx = p * 512 + lane * 8;
      const int row = idx >> 6, col = idx & 63;
      const u16x8 w = *(const u16x8*)(pw + idx);
      const size_t go = (size_t)(m0 + wm * 64 + row) * N + (n0 + wn * 64 + col);
      *(u16x8*)(Oh + go) = w;
    }
  } else {
    float* pw = (float*)lds + wid * 4096;   // 16 KB per wave (f32)
    float bv[4];
#pragma unroll
    for (int nf = 0; nf < 4; ++nf) bv[nf] = bias[n0 + wn * 64 + nf * 16 + l16];
#pragma unroll
    for (int m = 0; m < 4; ++m)
#pragma unroll
      for (int nf = 0; nf < 4; ++nf)
#pragma unroll
        for (int ii = 0; ii < 4; ++ii) {
          const int row = m * 16 + lkb * 4 + ii;
          pw[row * 64 + nf * 16 + l16] = acc[m][nf][ii] + bv[nf];
        }
#pragma unroll
    for (int p = 0; p < 16; ++p) {
      const int idx = p * 256 + lane * 4;
      const int row = idx >> 6, col = idx & 63;
      const float4 w = *(const float4*)(pw + idx);
      const size_t go = (size_t)(m0 + wm * 64 + row) * N + (n0 + wn * 64 + col);
      *(float4*)(Of + go) = w;
    }
  }
}

// ---------------------------------------------------------------------------
// LayerNorm with fused residual (x = xbuf + embed[seq[row]]), bf16 hidden out,
// fused gate score + L2 norm (computed in f32 BEFORE bf16 quantization, so
// selection precision is unchanged). One wave per 512-elem row.
// ---------------------------------------------------------------------------
__global__ __launch_bounds__(256)
void lnscore_k(const float* __restrict__ x, const int* __restrict__ seq,
               const float* __restrict__ embed,
               const float* __restrict__ g, const float* __restrict__ bt,
               const float* __restrict__ wg_w, const float* __restrict__ wg_b,
               ushort_t* __restrict__ hiddenH,
               float* __restrict__ scores, float* __restrict__ norms)
{
  const int wid = threadIdx.x >> 6, lane = threadIdx.x & 63;
  const int row = blockIdx.x * 4 + wid;
  const float* xr = x + (size_t)row * 512;
  const float* er = embed + (size_t)seq[row] * 512;
  float4 v0 = *(const float4*)(xr + lane*4);
  float4 v1 = *(const float4*)(xr + 256 + lane*4);
  const float4 e0 = *(const float4*)(er + lane*4);
  const float4 e1 = *(const float4*)(er + 256 + lane*4);
  v0.x += e0.x; v0.y += e0.y; v0.z += e0.z; v0.w += e0.w;
  v1.x += e1.x; v1.y += e1.y; v1.z += e1.z; v1.w += e1.w;
  float s = v0.x+v0.y+v0.z+v0.w + v1.x+v1.y+v1.z+v1.w;
  s = wsum64(s);
  const float mu = s * (1.f/512.f);
  float ss = (v0.x-mu)*(v0.x-mu) + (v0.y-mu)*(v0.y-mu)
           + (v0.z-mu)*(v0.z-mu) + (v0.w-mu)*(v0.w-mu)
           + (v1.x-mu)*(v1.x-mu) + (v1.y-mu)*(v1.y-mu)
           + (v1.z-mu)*(v1.z-mu) + (v1.w-mu)*(v1.w-mu);
  ss = wsum64(ss);
  const float inv = 1.f / sqrtf(ss * (1.f/512.f) + 1e-5f);
  const float4 g0 = *(const float4*)(g + lane*4);
  const float4 g1 = *(const float4*)(g + 256 + lane*4);
  const float4 c0 = *(const float4*)(bt + lane*4);
  const float4 c1 = *(const float4*)(bt + 256 + lane*4);
  float4 o0, o1;
  o0.x = (v0.x-mu)*inv*g0.x + c0.x;  o0.y = (v0.y-mu)*inv*g0.y + c0.y;
  o0.z = (v0.z-mu)*inv*g0.z + c0.z;  o0.w = (v0.w-mu)*inv*g0.w + c0.w;
  o1.x = (v1.x-mu)*inv*g1.x + c1.x;  o1.y = (v1.y-mu)*inv*g1.y + c1.y;
  o1.z = (v1.z-mu)*inv*g1.z + c1.z;  o1.w = (v1.w-mu)*inv*g1.w + c1.w;

  // f32 score + norm first (selection-critical)
  const float4 q0 = *(const float4*)(wg_w + lane*4);
  const float4 q1 = *(const float4*)(wg_w + 256 + lane*4);
  float d = o0.x*q0.x + o0.y*q0.y + o0.z*q0.z + o0.w*q0.w
          + o1.x*q1.x + o1.y*q1.y + o1.z*q1.z + o1.w*q1.w;
  float n2 = o0.x*o0.x + o0.y*o0.y + o0.z*o0.z + o0.w*o0.w
           + o1.x*o1.x + o1.y*o1.y + o1.z*o1.z + o1.w*o1.w;
  d = wsum64(d); n2 = wsum64(n2);
  const int b = row >> 10, t = row & 1023;
  if (lane == 0 && t < 1021) {
    scores[b * 1021 + t] = d + wg_b[0];
    norms[b * 1021 + t] = sqrtf(n2);
  }

  // bf16 hidden store
  u16x8 h;
  h[0]=f2bf(o0.x); h[1]=f2bf(o0.y); h[2]=f2bf(o0.z); h[3]=f2bf(o0.w);
  h[4]=f2bf(o1.x); h[5]=f2bf(o1.y); h[6]=f2bf(o1.z); h[7]=f2bf(o1.w);
  // interleave: elems 0..3 at lane*4, 4..7 at 256+lane*4
  ushort_t* hr = hiddenH + (size_t)row * 512;
  ushort4 lo, hi;
  lo.x=h[0]; lo.y=h[1]; lo.z=h[2]; lo.w=h[3];
  hi.x=h[4]; hi.y=h[5]; hi.z=h[6]; hi.w=h[7];
  *(ushort4*)(hr + lane*4) = lo;
  *(ushort4*)(hr + 256 + lane*4) = hi;
}

// ---------------------------------------------------------------------------
// Greedy score-ranked selection with cosine dedup; one block per batch row.
// hidden is bf16 now.
// ---------------------------------------------------------------------------
__global__ __launch_bounds__(256, 1)
void select_k(const ushort_t* __restrict__ hidden, const float* __restrict__ scores,
              const float* __restrict__ norms, int* __restrict__ selidx_g,
              int* __restrict__ selcnt_g)
{
  __shared__ __align__(16) ushort_t allH[128 * 520];     // 133120 B (keys alias)
  __shared__ ushort_t simS[64 * 128];
  __shared__ ushort_t sortedIdx[1024];
  __shared__ ushort_t selT[64];
  __shared__ ushort_t newPos[64];
  __shared__ int s_count, s_nacc;

  const int b = blockIdx.x, tid = threadIdx.x;
  const int wid = tid >> 6, lane = tid & 63;
  const int l16 = lane & 15, lkb = lane >> 4;

  unsigned long long* keys = (unsigned long long*)allH;
  for (int i = tid; i < 1024; i += 256) {
    const float s = (i < 1021) ? scores[b * 1021 + i] : -INFINITY;
    const unsigned u = __float_as_uint(s);
    const unsigned ms = (u & 0x80000000u) ? ~u : (u | 0x80000000u);
    keys[i] = ((unsigned long long)(~ms) << 32) | (unsigned)i;
  }
  __syncthreads();
  for (int k = 2; k <= 1024; k <<= 1) {
    for (int j = k >> 1; j > 0; j >>= 1) {
      for (int i = tid; i < 1024; i += 256) {
        const int ixj = i ^ j;
        if (ixj > i) {
          const unsigned long long a = keys[i], c = keys[ixj];
          const bool up = ((i & k) == 0);
          if ((a > c) == up) { keys[i] = c; keys[ixj] = a; }
        }
      }
      __syncthreads();
    }
  }
  for (int i = tid; i < 1024; i += 256)
    sortedIdx[i] = (ushort_t)(keys[i] & 0xffffu);
  if (tid == 0) s_count = 0;
  __syncthreads();

  int p = 0;
  while (true) {
    const int count = s_count;
    if (count >= 64 || p >= 1021) break;
    const int C = min(64, 1021 - p);

    {
      const int r = tid >> 2;
      const int seg = (tid & 3) * 128;
      if (r < C) {
        const int t = sortedIdx[p + r];
        const float rn = 1.f / fmaxf(norms[b * 1021 + t], 1e-12f);
        const ushort_t* src = hidden + ((size_t)b * 1024 + t) * 512 + seg;
        ushort_t* dst = allH + (64 + r) * 520 + seg;
#pragma unroll
        for (int u0 = 0; u0 < 128; u0 += 8) {
          const u16x8 x = *(const u16x8*)(src + u0);
          u16x8 o;
#pragma unroll
          for (int e = 0; e < 8; ++e) o[e] = f2bf(bf2f(x[e]) * rn);
          *(u16x8*)(dst + u0) = o;
        }
      }
    }
    __syncthreads();

    {
      f32x4 acc[8];
#pragma unroll
      for (int t = 0; t < 8; ++t) acc[t] = (f32x4){0.f, 0.f, 0.f, 0.f};
      const ushort_t* Abase = allH + (64 + (wid << 4) + l16) * 520;
#pragma unroll
      for (int ks = 0; ks < 16; ++ks) {
        const bf16x8 a = *(const bf16x8*)(Abase + ks * 32 + lkb * 8);
#pragma unroll
        for (int t = 0; t < 8; ++t) {
          const bf16x8 bb = *(const bf16x8*)(allH + ((t << 4) + l16) * 520 + ks * 32 + lkb * 8);
          acc[t] = __builtin_amdgcn_mfma_f32_16x16x32_bf16(a, bb, acc[t], 0, 0, 0);
        }
      }
#pragma unroll
      for (int t = 0; t < 8; ++t)
#pragma unroll
        for (int ii = 0; ii < 4; ++ii) {
          const int ri = (wid << 4) + lkb * 4 + ii;
          simS[ri * 128 + (t << 4) + l16] = f2bf(acc[t][ii]);
        }
    }
    __syncthreads();

    if (wid == 0) {
      unsigned long long accMask = 0ull;
      int nacc = 0;
      for (int i = 0; i < C; ++i) {
        float v = -INFINITY;
        if (lane < count) v = bf2f(simS[i * 128 + lane]);
        if ((accMask >> lane) & 1ull) v = fmaxf(v, bf2f(simS[i * 128 + 64 + lane]));
#pragma unroll
        for (int off = 32; off > 0; off >>= 1) v = fmaxf(v, __shfl_xor(v, off, 64));
        const int total = count + nacc;
        const bool ok = (total == 0) || (v <= 0.8f);
        if (total < 64 && ok) {
          if (lane == 0) { selT[total] = sortedIdx[p + i]; newPos[nacc] = (ushort_t)i; }
          accMask |= (1ull << i);
          ++nacc;
          if (total + 1 == 64) break;
        }
      }
      if (lane == 0) { s_nacc = nacc; s_count = count + nacc; }
    }
    __syncthreads();

    {
      const int nacc = s_nacc;
      for (int a = wid; a < nacc; a += 4) {
        const int srcrow = 64 + (int)newPos[a];
        const int dstrow = count + a;
        const u16x8 val = *(const u16x8*)(allH + srcrow * 520 + lane * 8);
        *(u16x8*)(allH + dstrow * 520 + lane * 8) = val;
      }
    }
    p += C;
    __syncthreads();
  }

  __syncthreads();
  if (tid < 64) selidx_g[b * 64 + tid] = (tid < s_count) ? (int)selT[tid] : 0;
  if (tid == 0) selcnt_g[b] = s_count;
}

// q = hidden[:, T-2, :] @ q_w^T + q_b ; one wave per output element
__global__ __launch_bounds__(256)
void q_k(const ushort_t* __restrict__ hidden, const float* __restrict__ q_w,
         const float* __restrict__ q_b, float* __restrict__ qv)
{
  const int wid = threadIdx.x >> 6, lane = threadIdx.x & 63;
  const int o = blockIdx.x * 4 + wid;
  const int b = o >> 9, n = o & 511;
  const ushort_t* hr = hidden + ((size_t)b*1024 + 1022) * 512 + lane * 8;
  const float* wr = q_w + (size_t)n * 512 + lane * 8;
  const u16x8 h8 = *(const u16x8*)hr;
  const float4 w0 = *(const float4*)wr;
  const float4 w1 = *(const float4*)(wr + 4);
  float d = bf2f(h8[0])*w0.x + bf2f(h8[1])*w0.y + bf2f(h8[2])*w0.z + bf2f(h8[3])*w0.w
          + bf2f(h8[4])*w1.x + bf2f(h8[5])*w1.y + bf2f(h8[6])*w1.z + bf2f(h8[7])*w1.w;
  d = wsum64(d);
  if (lane == 0) qv[o] = d + q_b[n];
}

// masked softmax attention over selected memory; one block per batch
__global__ __launch_bounds__(256)
void attn_k(const ushort_t* __restrict__ hidden, const float* __restrict__ qv,
            const int* __restrict__ selidx_g, const int* __restrict__ selcnt_g,
            float* __restrict__ ctx)
{
  const int b = blockIdx.x, tid = threadIdx.x;
  const int wid = tid >> 6, lane = tid & 63;
  __shared__ float qs[512];
  __shared__ int sidx[64];
  __shared__ float sv[64];
  __shared__ float av[64];
  const int count = selcnt_g[b];
  for (int i = tid; i < 512; i += 256) qs[i] = qv[b*512 + i];
  if (tid < 64) sidx[tid] = selidx_g[b*64 + tid];
  __syncthreads();
  for (int m = wid; m < 64; m += 4) {
    float sval = -1e9f;
    if (m < count) {
      const ushort_t* hr = hidden + ((size_t)b*1024 + sidx[m]) * 512 + lane * 8;
      const u16x8 a8 = *(const u16x8*)hr;
      const float* qp = &qs[lane * 8];
      float d = bf2f(a8[0])*qp[0] + bf2f(a8[1])*qp[1] + bf2f(a8[2])*qp[2]
              + bf2f(a8[3])*qp[3] + bf2f(a8[4])*qp[4] + bf2f(a8[5])*qp[5]
              + bf2f(a8[6])*qp[6] + bf2f(a8[7])*qp[7];
      d = wsum64(d);
      sval = d;
    }
    if (lane == 0) sv[m] = sval;
  }
  __syncthreads();
  if (tid < 64) {
    const float v = sv[tid];
    float mx = v;
#pragma unroll
    for (int off = 32; off > 0; off >>= 1) mx = fmaxf(mx, __shfl_xor(mx, off, 64));
    const float e = expf(v - mx);
    float ssum = e;
#pragma unroll
    for (int off = 32; off > 0; off >>= 1) ssum += __shfl_xor(ssum, off, 64);
    av[tid] = e / ssum;
  }
  __syncthreads();
  for (int n = tid; n < 512; n += 256) {
    float a = 0.f;
    for (int m = 0; m < count; ++m)
      a += av[m] * bf2f(hidden[((size_t)b*1024 + sidx[m]) * 512 + n]);
    ctx[b*512 + n] = a;
  }
}

// ---------------------------------------------------------------------------
// out = ctx @ out_w^T + out_b via 2-term streaming bf16 MFMA:
//   out ~= ch.wh + cl.wh   (ctx split hi/lo; w hi only -> no wl split VALU)
// ---------------------------------------------------------------------------
__global__ __launch_bounds__(256, 4)
void out_k(const float* __restrict__ ctx, const float* __restrict__ out_w,
           const float* __restrict__ out_b, float* __restrict__ out)
{
  __shared__ __align__(16) ushort_t ctxH[32 * 520];
  __shared__ __align__(16) ushort_t ctxL[32 * 520];
  const int tid = threadIdx.x;
  const int wid = tid >> 6, lane = tid & 63;
  const int l16 = lane & 15, lkb = lane >> 4;

  {
    const int row = tid >> 3;
    const int c0 = (tid & 7) * 64;
    const float* src = ctx + row * 512 + c0;
    ushort_t* dh = ctxH + row * 520 + c0;
    ushort_t* dl = ctxL + row * 520 + c0;
#pragma unroll
    for (int u0 = 0; u0 < 64; u0 += 8) {
      const float4 a = *(const float4*)(src + u0);
      const float4 b = *(const float4*)(src + u0 + 4);
      u16x8 h, l;
      split8(a, b, h, l);
      *(u16x8*)(dh + u0) = h;
      *(u16x8*)(dl + u0) = l;
    }
  }
  __syncthreads();

  const int v = blockIdx.x * 64 + wid * 16 + l16;
  const float* wr = out_w + (size_t)v * 512 + lkb * 8;
  f32x4 acc0 = (f32x4){0.f, 0.f, 0.f, 0.f};
  f32x4 acc1 = (f32x4){0.f, 0.f, 0.f, 0.f};
#pragma unroll
  for (int ks = 0; ks < 16; ++ks) {
    const float4 wa = *(const float4*)(wr + ks * 32);
    const float4 wb = *(const float4*)(wr + ks * 32 + 4);
    u16x8 wh;
    wh[0]=f2bf(wa.x); wh[1]=f2bf(wa.y); wh[2]=f2bf(wa.z); wh[3]=f2bf(wa.w);
    wh[4]=f2bf(wb.x); wh[5]=f2bf(wb.y); wh[6]=f2bf(wb.z); wh[7]=f2bf(wb.w);
    const bf16x8 whb = (bf16x8)wh;
    const int co = ks * 32 + lkb * 8;
    const bf16x8 ch0 = *(const bf16x8*)(ctxH + l16 * 520 + co);
    const bf16x8 cl0 = *(const bf16x8*)(ctxL + l16 * 520 + co);
    const bf16x8 ch1 = *(const bf16x8*)(ctxH + (16 + l16) * 520 + co);
    const bf16x8 cl1 = *(const bf16x8*)(ctxL + (16 + l16) * 520 + co);
    acc0 = __builtin_amdgcn_mfma_f32_16x16x32_bf16(ch0, whb, acc0, 0, 0, 0);
    acc0 = __builtin_amdgcn_mfma_f32_16x16x32_bf16(cl0, whb, acc0, 0, 0, 0);
    acc1 = __builtin_amdgcn_mfma_f32_16x16x32_bf16(ch1, whb, acc1, 0, 0, 0);
    acc1 = __builtin_amdgcn_mfma_f32_16x16x32_bf16(cl1, whb, acc1, 0, 0, 0);
  }
  const float bv = out_b[v];
#pragma unroll
  for (int i = 0; i < 4; ++i) {
    out[(size_t)(lkb * 4 + i) * 32000 + v] = acc0[i] + bv;
    out[(size_t)(16 + lkb * 4 + i) * 32000 + v] = acc1[i] + bv;
  }
}

extern "C" void kernel_launch(void* const* d_in, const int* in_sizes, int n_in,
                              void* d_out, int out_size, void* d_ws, size_t ws_size,
                              hipStream_t stream)
{
  const int*   seq   = (const int*)d_in[0];
  const float* embed = (const float*)d_in[1];
  const float* w1    = (const float*)d_in[2];
  const float* b1    = (const float*)d_in[3];
  const float* w2    = (const float*)d_in[4];
  const float* b2    = (const float*)d_in[5];
  const float* ln_g  = (const float*)d_in[6];
  const float* ln_b  = (const float*)d_in[7];
  const float* wg_w  = (const float*)d_in[8];
  const float* wg_b  = (const float*)d_in[9];
  const float* q_w   = (const float*)d_in[10];
  const float* q_b   = (const float*)d_in[11];
  const float* out_w = (const float*)d_in[12];
  const float* out_b = (const float*)d_in[13];
  float* out = (float*)d_out;

  char* ws = (char*)d_ws;
  size_t off = 0;
  auto alloc = [&](size_t bytes) {
    void* p = ws + off;
    off += (bytes + 255) & ~(size_t)255;
    return p;
  };
  void* xA = alloc((size_t)32768 * 512 * 4);            // 67 MB (Ah/Al -> xbuf)
  ushort_t* Ahid = (ushort_t*)xA;
  ushort_t* Alid = Ahid + (size_t)32768 * 512;
  float* xbuf = (float*)xA;
  ushort_t* ff1h = (ushort_t*)alloc((size_t)32768 * 1024 * 2);  // 67 MB
  ushort_t* hidH = (ushort_t*)alloc((size_t)32768 * 512 * 2);   // 33.5 MB
  ushort_t* w1h = (ushort_t*)alloc((size_t)1024 * 512 * 2);
  ushort_t* w2h = (ushort_t*)alloc((size_t)512 * 1024 * 2);
  float* scores = (float*)alloc((size_t)32 * 1021 * 4);
  float* norms  = (float*)alloc((size_t)32 * 1021 * 4);
  int*   selidx = (int*)alloc((size_t)32 * 64 * 4);
  int*   selcnt = (int*)alloc((size_t)32 * 4);
  float* qbuf   = (float*)alloc((size_t)32 * 512 * 4);
  float* ctxb   = (float*)alloc((size_t)32 * 512 * 4);

  // fused pre-split (gather hi/lo + w1 hi + w2 hi)
  presplit<<<8704, 256, 0, stream>>>(seq, embed, Ahid, Alid,
                                     w1, w1h, w2, w2h);

  // FF1: relu(h @ w1^T + b1) -> ff1 hi bf16  [32768,1024]  (2-term A)
  gemmk<0, 2><<<2048, 256, 0, stream>>>(Ahid, Alid, w1h, b1,
                                        ff1h, nullptr, 1024, 512);
  // FF2: ff1h @ w2h^T + b2 -> xbuf f32 [32768,512]  (1-term; resid in LN)
  gemmk<1, 1><<<1024, 256, 0, stream>>>(ff1h, ff1h, w2h, b2,
                                        nullptr, xbuf, 512, 1024);
  // LN (+resid) -> bf16 hidden + f32 scores/norms
  lnscore_k<<<8192, 256, 0, stream>>>(xbuf, seq, embed, ln_g, ln_b,
                                      wg_w, wg_b, hidH, scores, norms);
  select_k<<<32, 256, 0, stream>>>(hidH, scores, norms, selidx, selcnt);
  q_k<<<4096, 256, 0, stream>>>(hidH, q_w, q_b, qbuf);
  attn_k<<<32, 256, 0, stream>>>(hidH, qbuf, selidx, selcnt, ctxb);
  out_k<<<500, 256, 0, stream>>>(ctxb, out_w, out_b, out);
}